// Round 13
// baseline (145.806 us; speedup 1.0000x reference)
//
#include <hip/hip_runtime.h>

// ---------------------------------------------------------------------------
// B=4, N1=1024, N2=1024, D=256, H=4, Dh=64
//   u[b,i,4] = gelu(prev@W_pre+b_pre) @ W_fuse[0:6]
//   v[b,j,4] = gelu(curr@W_cur+b_cur) @ W_fuse[6:12] + b_fuse
//   c = mask ? u_i+v_j : 0
//   Gd_j[8] = gelu(d_j)@W_ffn[4:8] + gelu(e_j)@W_ffn[8:12] + b_ffn
//   logits = gelu(gelu(c)@W_ffn[0:4] + Gd_j)@W_fcc + b_fcc
//   softmax over i WITHOUT max-subtraction (masked -> w=0); plain-sum partials
//   res = P @ prev (per-head);  g_j = (T_j@W_ffn[0:4]+cnt*Gd_j)/(cnt+1)
//   out = res + gelu(g)@W_fcg + b_fcg
// Round-12 lesson: work-reduction (pk_fma, compaction) gave ~2% each while
//   static VALU count says ~18us of issue vs 94.6us wall -> ~75% stalled on
//   the 4-barrier/chunk phase structure. Fix: SPLIT k_main into two
//   barrier-free kernels (k_logit -> global wW -> k_pv); plain-sum softmax
//   makes the decoupling exact. Tier on ws_size; round-12 fused kept as
//   fallback.
// Round-9 lesson: exp once at w-write. Round-7: balance cols/thread vs VMEM.
// Round-6: denominators are PER (column, HEAD). Round-5: >128 VGPR cliff.
// Round-4: never cap __launch_bounds__ min-waves (spill -> HBM).
// ---------------------------------------------------------------------------

typedef float v2f __attribute__((ext_vector_type(2)));
__device__ __forceinline__ v2f pk_fma(v2f a, v2f b, v2f c){
    return __builtin_elementwise_fma(a, b, c);
}

__device__ __forceinline__ float gelu_f(float x){
    float x2 = x*x;
    float tt = x * __builtin_fmaf(0.044715f, x2, 1.0f);   // x + 0.044715 x^3
    float e  = exp2f(2.3022082f * tt);                    // exp(1.59576912*tt)
    return x - __fdividef(x, e + 1.0f);
}

// ---- kernel 1: per-row u (prev side) and v (curr side), one wave per row ----
__global__ __launch_bounds__(256) void k_rows(
    const float* __restrict__ prev, const float* __restrict__ curr,
    const float* __restrict__ W_pre, const float* __restrict__ b_pre,
    const float* __restrict__ W_cur, const float* __restrict__ b_cur,
    const float* __restrict__ W_fuse, const float* __restrict__ b_fuse,
    float* __restrict__ u_ws, float* __restrict__ v_ws)
{
    int gid  = blockIdx.x * 256 + threadIdx.x;
    int wave = gid >> 6;
    int lane = threadIdx.x & 63;
    bool isPrev = wave < 4096;
    int row = isPrev ? wave : (wave - 4096);
    const float* xrow = (isPrev ? prev : curr) + (size_t)row * 256;
    const float* W  = isPrev ? W_pre : W_cur;
    const float* bv = isPrev ? b_pre : b_cur;

    float4 x4 = *reinterpret_cast<const float4*>(xrow + lane*4);
    const float* Wl = W + lane*24;
    float p[6];
    #pragma unroll
    for (int k=0;k<6;++k)
        p[k] = x4.x*Wl[k] + x4.y*Wl[6+k] + x4.z*Wl[12+k] + x4.w*Wl[18+k];
    #pragma unroll
    for (int off=32; off>=1; off>>=1){
        #pragma unroll
        for (int k=0;k<6;++k) p[k] += __shfl_xor(p[k], off, 64);
    }
    if (lane == 0){
        float g[6];
        #pragma unroll
        for(int k=0;k<6;++k) g[k] = gelu_f(p[k] + bv[k]);
        int rb = isPrev ? 0 : 6;
        float o[4];
        #pragma unroll
        for(int kk=0;kk<4;++kk){
            float a = isPrev ? 0.0f : b_fuse[kk];
            #pragma unroll
            for(int k=0;k<6;++k) a += g[k]*W_fuse[(rb+k)*4+kk];
            o[kk]=a;
        }
        float* dst = (isPrev ? u_ws : v_ws) + (size_t)row*4;
        *reinterpret_cast<float4*>(dst) = make_float4(o[0],o[1],o[2],o[3]);
    }
}

// ---- kernel 2: per-column reductions over edges + Gd precompute ----
__global__ __launch_bounds__(256) void k_cols(
    const int* __restrict__ edges,
    const float* __restrict__ u_ws, const float* __restrict__ v_ws,
    const float* __restrict__ W_ffn, const float* __restrict__ b_ffn,
    float* __restrict__ Gd_ws, float* __restrict__ cnt_ws)
{
    int b  = blockIdx.x >> 6;
    int j0 = (blockIdx.x & 63) * 16;
    int t  = threadIdx.x;
    int jq = t & 3, sl = t >> 2;
    const int*   eb = edges + (size_t)b*1048576 + j0 + jq*4;
    const float* ub = u_ws + (size_t)b*4096;

    int   cnt[4] = {0,0,0,0};
    float S[4][4] = {{0.f}};
    float M[4][4];
    #pragma unroll
    for (int q=0;q<4;++q)
        #pragma unroll
        for (int k=0;k<4;++k) M[q][k] = -3.4e38f;

    #pragma unroll 4
    for (int ii=0; ii<16; ++ii){
        int i = sl*16 + ii;
        int4   e4 = *reinterpret_cast<const int4*>(eb + (size_t)i*1024);
        float4 u4 = *reinterpret_cast<const float4*>(ub + i*4);
        float uu[4] = {u4.x,u4.y,u4.z,u4.w};
        int   ee[4] = {e4.x,e4.y,e4.z,e4.w};
        #pragma unroll
        for (int q=0;q<4;++q){
            bool mk = ee[q]!=0;
            cnt[q] += mk ? 1 : 0;
            #pragma unroll
            for (int k=0;k<4;++k){
                S[q][k] += mk ? uu[k] : 0.0f;
                M[q][k]  = mk ? fmaxf(M[q][k],uu[k]) : M[q][k];
            }
        }
    }
    __shared__ float rS[64][16][4];
    __shared__ float rM[64][16][4];
    __shared__ int   rC[64][16];
    #pragma unroll
    for (int q=0;q<4;++q){
        int c = jq*4+q;
        #pragma unroll
        for (int k=0;k<4;++k){ rS[sl][c][k]=S[q][k]; rM[sl][c][k]=M[q][k]; }
        rC[sl][c]=cnt[q];
    }
    __syncthreads();
    float aS[4], aM[4]; int aC=0; int c2=0, hf=0;
    if (t < 128){
        c2 = t & 15; hf = t >> 4;
        #pragma unroll
        for(int k=0;k<4;++k){ aS[k]=0.f; aM[k]=-3.4e38f; }
        for (int s2=hf*8; s2<hf*8+8; ++s2){
            aC += rC[s2][c2];
            #pragma unroll
            for(int k=0;k<4;++k){ aS[k]+=rS[s2][c2][k]; aM[k]=fmaxf(aM[k],rM[s2][c2][k]); }
        }
    }
    __syncthreads();
    if (t < 128){
        rC[hf][c2]=aC;
        #pragma unroll
        for(int k=0;k<4;++k){ rS[hf][c2][k]=aS[k]; rM[hf][c2][k]=aM[k]; }
    }
    __syncthreads();
    if (t < 16){
        int cc=0; float Sa[4]={0,0,0,0};
        float Ma[4]={-3.4e38f,-3.4e38f,-3.4e38f,-3.4e38f};
        for (int s2=0;s2<8;++s2){
            cc += rC[s2][t];
            #pragma unroll
            for(int k=0;k<4;++k){ Sa[k]+=rS[s2][t][k]; Ma[k]=fmaxf(Ma[k],rM[s2][t][k]); }
        }
        size_t cj = (size_t)b*1024 + j0 + t;
        float4 v4 = *reinterpret_cast<const float4*>(v_ws + cj*4);
        float vv[4]={v4.x,v4.y,v4.z,v4.w};
        float cf = (float)cc, e1 = cf + 1.0f;
        float gd[4], ge[4];
        #pragma unroll
        for(int k=0;k<4;++k){
            float dk = (Sa[k] + cf*vv[k]) / e1;
            float ek;
            if (cc == 0) ek = 0.0f;
            else { float m1 = Ma[k]+vv[k]; ek = (cc < 1024) ? fmaxf(m1, 0.0f) : m1; }
            gd[k]=gelu_f(dk); ge[k]=gelu_f(ek);
        }
        #pragma unroll
        for(int kk=0;kk<8;++kk){
            float a = b_ffn[kk];
            #pragma unroll
            for(int k=0;k<4;++k)
                a += gd[k]*W_ffn[(4+k)*8+kk] + ge[k]*W_ffn[(8+k)*8+kk];
            Gd_ws[cj*8+kk]=a;
        }
        cnt_ws[cj]=cf;
    }
}

// ---- kernel 3a: barrier-free logit kernel -> wW (exp'd weights) + Tws ----
// Block = (b-b_off, jt, sp). 256 threads, thread = (il_w=t>>3, jl_w=t&7),
// rows il_w+32k for k<RPB/32. No LDS in main loop; 2 tail barriers for T.
// wW layout: [wp][row_local][h*8+jl] (stride 32) = k_pv's read layout.
template<int SPLIT>
__global__ __launch_bounds__(256) void k_logit(
    const int* __restrict__ edges,
    const float* __restrict__ u_ws, const float* __restrict__ v_ws,
    const float* __restrict__ Gd_ws,
    const float* __restrict__ W_ffn, const float* __restrict__ W_fcc,
    const float* __restrict__ b_fcc,
    float* __restrict__ wW, float* __restrict__ Tws, int b_off)
{
    const int RPB = 1024/SPLIT;
    int bid = blockIdx.x;
    int sp  = bid & (SPLIT-1);
    int jt  = (bid / SPLIT) & 127;
    int b   = b_off + bid / (SPLIT*128);
    int j0  = jt*8;
    int t   = threadIdx.x;
    int jl_w = t & 7, il_w = t >> 3;

    __shared__ float sT[32][8][4];

    size_t cj = (size_t)b*1024 + j0 + jl_w;
    float4 v4p = *reinterpret_cast<const float4*>(v_ws + cj*4);
    float4 gd0 = *reinterpret_cast<const float4*>(Gd_ws + cj*8);
    float4 gd1 = *reinterpret_cast<const float4*>(Gd_ws + cj*8 + 4);
    float gdv[8] = {gd0.x,gd0.y,gd0.z,gd0.w,gd1.x,gd1.y,gd1.z,gd1.w};

    const float LOG2E = 1.4426950408889634f;
    float W4r[4][8], Wfc[8][4], bfc[4];
    #pragma unroll
    for(int k=0;k<4;++k)
        #pragma unroll
        for(int kk=0;kk<8;++kk) W4r[k][kk]=W_ffn[k*8+kk];
    #pragma unroll
    for(int kk=0;kk<8;++kk)
        #pragma unroll
        for(int hh=0;hh<4;++hh) Wfc[kk][hh]=W_fcc[kk*4+hh]*LOG2E;
    #pragma unroll
    for(int hh=0;hh<4;++hh) bfc[hh]=b_fcc[hh]*LOG2E;

    float Tp[4] = {0,0,0,0};
    const int*   eb = edges + (size_t)b*1048576 + j0 + jl_w;
    const float* ub = u_ws + (size_t)b*4096;
    size_t wp = ((size_t)(b - b_off)*128 + jt)*SPLIT + sp;
    float* wbase = wW + wp*(size_t)RPB*32;
    int base_i0 = sp*RPB;

    for (int k=0; k<RPB/32; ++k){
        int rl  = k*32 + il_w;
        int row = base_i0 + rl;
        int eg = eb[(size_t)row*1024];
        float4 u4 = *reinterpret_cast<const float4*>(ub + (size_t)row*4);
        float g0 = gelu_f(u4.x + v4p.x);
        float g1 = gelu_f(u4.y + v4p.y);
        float g2 = gelu_f(u4.z + v4p.z);
        float g3 = gelu_f(u4.w + v4p.w);
        Tp[0] += eg ? g0 : 0.0f;
        Tp[1] += eg ? g1 : 0.0f;
        Tp[2] += eg ? g2 : 0.0f;
        Tp[3] += eg ? g3 : 0.0f;
        float fu[8];
        #pragma unroll
        for (int kk=0;kk<8;++kk){
            float a = gdv[kk];
            a = __builtin_fmaf(g0, W4r[0][kk], a);
            a = __builtin_fmaf(g1, W4r[1][kk], a);
            a = __builtin_fmaf(g2, W4r[2][kk], a);
            a = __builtin_fmaf(g3, W4r[3][kk], a);
            fu[kk] = gelu_f(a);
        }
        float* wd = wbase + (size_t)rl*32 + jl_w;
        #pragma unroll
        for (int hh=0;hh<4;++hh){
            float a = bfc[hh];
            #pragma unroll
            for (int kk=0;kk<8;++kk) a = __builtin_fmaf(fu[kk], Wfc[kk][hh], a);
            wd[hh*8] = eg ? exp2f(a) : 0.0f;
        }
    }

    // ---- tail: T reduction ----
    #pragma unroll
    for (int k=0;k<4;++k) sT[il_w][jl_w][k] = Tp[k];
    __syncthreads();
    size_t bp = ((size_t)b*128 + jt)*SPLIT + sp;
    if (t < 8){
        float T0=0,T1=0,T2=0,T3=0;
        for (int s2=0;s2<32;++s2){
            T0+=sT[s2][t][0]; T1+=sT[s2][t][1];
            T2+=sT[s2][t][2]; T3+=sT[s2][t][3];
        }
        float* td = Tws + (bp*8 + t)*4;
        td[0]=T0; td[1]=T1; td[2]=T2; td[3]=T3;
    }
}

// ---- kernel 3b: barrier-free PV kernel: reads wW + prev, packed-FMA ----
// Block = (b-b_off, jt, sp). Roles (jh=t&1, h=(t>>1)&3, dq=(t>>3)&7, ig=t>>6):
// 4 cols x 8 dims, rows ig*16..+16 per 64-chunk. Tail-only ig-merge.
template<int SPLIT>
__global__ __launch_bounds__(256) void k_pv(
    const float* __restrict__ prev, const float* __restrict__ wW,
    float* __restrict__ Pws, float* __restrict__ Sws, int b_off)
{
    const int RPB = 1024/SPLIT;
    int bid = blockIdx.x;
    int sp  = bid & (SPLIT-1);
    int jt  = (bid / SPLIT) & 127;
    int b   = b_off + bid / (SPLIT*128);
    int t   = threadIdx.x;
    int jh = t & 1, h = (t >> 1) & 3, dq = (t >> 3) & 7, ig = t >> 6;

    __shared__ __align__(16) float sBuf[2368];   // 64*37 merge buffer

    v2f sA = {0,0}, sB = {0,0};
    v2f acc2[4][4];
    #pragma unroll
    for (int c=0;c<4;++c)
        #pragma unroll
        for (int e=0;e<4;++e) acc2[c][e] = (v2f){0.f,0.f};

    size_t wp = ((size_t)(b - b_off)*128 + jt)*SPLIT + sp;
    const float* wbase = wW + (wp*(size_t)RPB + ig*16)*32 + h*8 + jh*4;
    const float* pbase = prev + (size_t)b*262144
                       + (size_t)(sp*RPB + ig*16)*256 + h*64 + dq*8;

    for (int cc=0; cc<RPB/64; ++cc){
        const float* lw = wbase + (size_t)cc*64*32;
        const float* pc = pbase + (size_t)cc*64*256;
        #pragma unroll 4
        for (int i=0;i<16;++i){
            float4 lv = *reinterpret_cast<const float4*>(lw + i*32);
            float4 a0 = *reinterpret_cast<const float4*>(pc + (size_t)i*256);
            float4 a1 = *reinterpret_cast<const float4*>(pc + (size_t)i*256 + 4);
            sA += (v2f){lv.x, lv.y};
            sB += (v2f){lv.z, lv.w};
            v2f p01 = {a0.x,a0.y}, p23 = {a0.z,a0.w};
            v2f p45 = {a1.x,a1.y}, p67 = {a1.z,a1.w};
            v2f w0 = {lv.x,lv.x}, w1 = {lv.y,lv.y};
            v2f w2 = {lv.z,lv.z}, w3 = {lv.w,lv.w};
            acc2[0][0]=pk_fma(w0,p01,acc2[0][0]); acc2[0][1]=pk_fma(w0,p23,acc2[0][1]);
            acc2[0][2]=pk_fma(w0,p45,acc2[0][2]); acc2[0][3]=pk_fma(w0,p67,acc2[0][3]);
            acc2[1][0]=pk_fma(w1,p01,acc2[1][0]); acc2[1][1]=pk_fma(w1,p23,acc2[1][1]);
            acc2[1][2]=pk_fma(w1,p45,acc2[1][2]); acc2[1][3]=pk_fma(w1,p67,acc2[1][3]);
            acc2[2][0]=pk_fma(w2,p01,acc2[2][0]); acc2[2][1]=pk_fma(w2,p23,acc2[2][1]);
            acc2[2][2]=pk_fma(w2,p45,acc2[2][2]); acc2[2][3]=pk_fma(w2,p67,acc2[2][3]);
            acc2[3][0]=pk_fma(w3,p01,acc2[3][0]); acc2[3][1]=pk_fma(w3,p23,acc2[3][1]);
            acc2[3][2]=pk_fma(w3,p45,acc2[3][2]); acc2[3][3]=pk_fma(w3,p67,acc2[3][3]);
        }
    }

    float s4[4] = {sA[0], sA[1], sB[0], sB[1]};

    // ---- tail ig-merge, single 64-slot buffer, 3 rounds (plain sums) ----
    int r64 = t & 63;
    #pragma unroll
    for (int g = 3; g >= 1; --g){
        __syncthreads();
        if (ig == g){
            float* dst = sBuf + (size_t)r64*37;
            #pragma unroll
            for (int c=0;c<4;++c) dst[c] = s4[c];
            #pragma unroll
            for (int c=0;c<4;++c)
                #pragma unroll
                for (int e=0;e<4;++e){
                    dst[4 + c*8 + 2*e    ] = acc2[c][e][0];
                    dst[4 + c*8 + 2*e + 1] = acc2[c][e][1];
                }
        }
        __syncthreads();
        if (ig == 0){
            const float* src = sBuf + (size_t)t*37;
            #pragma unroll
            for (int c=0;c<4;++c) s4[c] += src[c];
            #pragma unroll
            for (int c=0;c<4;++c)
                #pragma unroll
                for (int e=0;e<4;++e){
                    acc2[c][e][0] += src[4 + c*8 + 2*e    ];
                    acc2[c][e][1] += src[4 + c*8 + 2*e + 1];
                }
        }
    }

    size_t bp = ((size_t)b*128 + jt)*SPLIT + sp;
    if (ig == 0){
        if (dq == 0){
            #pragma unroll
            for (int c=0;c<4;++c)
                Sws[bp*32 + h*8 + jh*4 + c] = s4[c];
        }
        #pragma unroll
        for (int c=0;c<4;++c){
            float* dst = Pws + (((size_t)bp*8 + jh*4 + c)*32 + h*8 + dq)*8;
            float4* d4 = reinterpret_cast<float4*>(dst);
            d4[0] = make_float4(acc2[c][0][0],acc2[c][0][1],acc2[c][1][0],acc2[c][1][1]);
            d4[1] = make_float4(acc2[c][2][0],acc2[c][2][1],acc2[c][3][0],acc2[c][3][1]);
        }
    }
}

// ---- kernel 3 (FALLBACK): round-12 fused two-pass compacted k_main ----
template<int SPLIT>
__global__ __launch_bounds__(256) void k_main(
    const float* __restrict__ prev, const int* __restrict__ edges,
    const float* __restrict__ u_ws, const float* __restrict__ v_ws,
    const float* __restrict__ Gd_ws,
    const float* __restrict__ W_ffn, const float* __restrict__ W_fcc,
    const float* __restrict__ b_fcc,
    float* __restrict__ Pws, float* __restrict__ Sws, float* __restrict__ Tws)
{
    int bid = blockIdx.x;
    int sp  = bid & (SPLIT-1);
    int jt  = (bid / SPLIT) & 127;
    int b   = bid / (SPLIT*128);
    int j0  = jt*8;
    int t   = threadIdx.x;
    int lane = t & 63;
    int wv   = t >> 6;
    int jl_w = t & 7, il_w = t >> 3;
    int jh = t & 1, h = (t >> 1) & 3, dq = (t >> 3) & 7, ig = t >> 6;

    __shared__ __align__(16) float sBuf[2368];
    __shared__ __align__(16) float sU[64][4];
    __shared__ __align__(16) float sV[8][4];
    __shared__ __align__(16) float sGd[8][8];
    __shared__ __align__(16) float sGc[512][4];
    __shared__ unsigned short sPairs[512];
    __shared__ unsigned long long sBal[8];
    float* sLog = sBuf;

    if (t < 32) (&sV[0][0])[t]  = v_ws[((size_t)b*1024 + j0)*4 + t];
    if (t < 64) (&sGd[0][0])[t] = Gd_ws[((size_t)b*1024 + j0)*8 + t];

    float W4r[4][8], Wfc[8][4], bfc[4];
    #pragma unroll
    for(int k=0;k<4;++k)
        #pragma unroll
        for(int kk=0;kk<8;++kk) W4r[k][kk]=W_ffn[k*8+kk];
    #pragma unroll
    for(int kk=0;kk<8;++kk)
        #pragma unroll
        for(int hh=0;hh<4;++hh) Wfc[kk][hh]=W_fcc[kk*4+hh];
    #pragma unroll
    for(int hh=0;hh<4;++hh) bfc[hh]=b_fcc[hh];

    v2f sA = {0,0}, sB = {0,0};
    v2f acc2[4][4];
    #pragma unroll
    for (int c=0;c<4;++c)
        #pragma unroll
        for (int e=0;e<4;++e) acc2[c][e] = (v2f){0.f,0.f};
    float Tp[4] = {0,0,0,0};

    const int*   ebase  = edges + (size_t)b*1048576 + j0;
    const float* pbBase = prev  + (size_t)b*262144 + h*64 + dq*8;

    const int NCH = 16/SPLIT;
    const int base_i0 = sp*(1024/SPLIT);

    __syncthreads();
    float4 v4p = *reinterpret_cast<const float4*>(&sV[jl_w][0]);

    float su_r = u_ws[((size_t)b*1024 + base_i0)*4 + t];
    int   egr0 = ebase[(size_t)(base_i0+il_w   )*1024 + jl_w];
    int   egr1 = ebase[(size_t)(base_i0+il_w+32)*1024 + jl_w];

    for (int cc=0; cc<NCH; ++cc){
        int i0 = base_i0 + cc*64;
        (&sU[0][0])[t] = su_r;
        __syncthreads();

        int eg2[2] = {egr0, egr1};
        #pragma unroll
        for (int r=0;r<2;++r){
            int il = il_w + 32*r;
            int eg = eg2[r];
            float4 u4 = *reinterpret_cast<const float4*>(&sU[il][0]);
            float g0 = gelu_f(u4.x + v4p.x);
            float g1 = gelu_f(u4.y + v4p.y);
            float g2 = gelu_f(u4.z + v4p.z);
            float g3 = gelu_f(u4.w + v4p.w);
            Tp[0] += eg ? g0 : 0.0f;
            Tp[1] += eg ? g1 : 0.0f;
            Tp[2] += eg ? g2 : 0.0f;
            Tp[3] += eg ? g3 : 0.0f;
            int pid = il*8 + jl_w;
            *reinterpret_cast<float4*>(&sGc[pid][0]) = make_float4(g0,g1,g2,g3);
            sLog[il*36 +  0 + jl_w] = 0.0f;
            sLog[il*36 +  8 + jl_w] = 0.0f;
            sLog[il*36 + 16 + jl_w] = 0.0f;
            sLog[il*36 + 24 + jl_w] = 0.0f;
        }
        unsigned long long b0 = __ballot(egr0 != 0);
        unsigned long long b1 = __ballot(egr1 != 0);
        if (lane == 0){ sBal[wv*2] = b0; sBal[wv*2+1] = b1; }
        __syncthreads();
        int base = 0, total = 0;
        #pragma unroll
        for (int w2 = 0; w2 < 4; ++w2){
            int c = __popcll(sBal[2*w2]) + __popcll(sBal[2*w2+1]);
            if (w2 < wv) base += c;
            total += c;
        }
        unsigned long long lm = (1ull << lane) - 1ull;
        int p0 = base + (int)__popcll(b0 & lm);
        int p1 = base + (int)__popcll(b0) + (int)__popcll(b1 & lm);
        if (egr0) sPairs[p0] = (unsigned short)(il_w*8 + jl_w);
        if (egr1) sPairs[p1] = (unsigned short)((il_w+32)*8 + jl_w);

        {
            int i0n = base_i0 + ((cc+1 < NCH) ? (cc+1)*64 : 0);
            su_r = u_ws[((size_t)b*1024 + i0n)*4 + t];
            egr0 = ebase[(size_t)(i0n+il_w   )*1024 + jl_w];
            egr1 = ebase[(size_t)(i0n+il_w+32)*1024 + jl_w];
        }
        __syncthreads();

        for (int p = t; p < total; p += 256){
            int pid = sPairs[p];
            int il = pid >> 3, jl = pid & 7;
            float4 gcv = *reinterpret_cast<const float4*>(&sGc[pid][0]);
            float4 gd0 = *reinterpret_cast<const float4*>(&sGd[jl][0]);
            float4 gd1 = *reinterpret_cast<const float4*>(&sGd[jl][4]);
            float gdv[8] = {gd0.x,gd0.y,gd0.z,gd0.w,gd1.x,gd1.y,gd1.z,gd1.w};
            float fu[8];
            #pragma unroll
            for (int kk=0;kk<8;++kk){
                float a = gdv[kk];
                a = __builtin_fmaf(gcv.x, W4r[0][kk], a);
                a = __builtin_fmaf(gcv.y, W4r[1][kk], a);
                a = __builtin_fmaf(gcv.z, W4r[2][kk], a);
                a = __builtin_fmaf(gcv.w, W4r[3][kk], a);
                fu[kk] = gelu_f(a);
            }
            #pragma unroll
            for (int hh=0;hh<4;++hh){
                float a = bfc[hh];
                #pragma unroll
                for (int kk=0;kk<8;++kk) a = __builtin_fmaf(fu[kk], Wfc[kk][hh], a);
                sLog[il*36 + hh*8 + jl] = exp2f(a * 1.4426950408889634f);
            }
        }
        __syncthreads();

        const float* pc = pbBase + (size_t)(i0 + ig*16)*256;
        const float* lg = sLog + (ig*16)*36 + h*8 + jh*4;
        #pragma unroll 4
        for (int i=0;i<16;++i){
            float4 lv = *reinterpret_cast<const float4*>(lg + i*36);
            float4 a0 = *reinterpret_cast<const float4*>(pc + (size_t)i*256);
            float4 a1 = *reinterpret_cast<const float4*>(pc + (size_t)i*256 + 4);
            sA += (v2f){lv.x, lv.y};
            sB += (v2f){lv.z, lv.w};
            v2f p01 = {a0.x,a0.y}, p23 = {a0.z,a0.w};
            v2f p45 = {a1.x,a1.y}, p67 = {a1.z,a1.w};
            v2f w0 = {lv.x,lv.x}, w1 = {lv.y,lv.y};
            v2f w2 = {lv.z,lv.z}, w3 = {lv.w,lv.w};
            acc2[0][0]=pk_fma(w0,p01,acc2[0][0]); acc2[0][1]=pk_fma(w0,p23,acc2[0][1]);
            acc2[0][2]=pk_fma(w0,p45,acc2[0][2]); acc2[0][3]=pk_fma(w0,p67,acc2[0][3]);
            acc2[1][0]=pk_fma(w1,p01,acc2[1][0]); acc2[1][1]=pk_fma(w1,p23,acc2[1][1]);
            acc2[1][2]=pk_fma(w1,p45,acc2[1][2]); acc2[1][3]=pk_fma(w1,p67,acc2[1][3]);
            acc2[2][0]=pk_fma(w2,p01,acc2[2][0]); acc2[2][1]=pk_fma(w2,p23,acc2[2][1]);
            acc2[2][2]=pk_fma(w2,p45,acc2[2][2]); acc2[2][3]=pk_fma(w2,p67,acc2[2][3]);
            acc2[3][0]=pk_fma(w3,p01,acc2[3][0]); acc2[3][1]=pk_fma(w3,p23,acc2[3][1]);
            acc2[3][2]=pk_fma(w3,p45,acc2[3][2]); acc2[3][3]=pk_fma(w3,p67,acc2[3][3]);
        }
    }

    float s4[4] = {sA[0], sA[1], sB[0], sB[1]};

    int r64 = t & 63;
    #pragma unroll
    for (int g = 3; g >= 1; --g){
        __syncthreads();
        if (ig == g){
            float* dst = sBuf + (size_t)r64*37;
            #pragma unroll
            for (int c=0;c<4;++c) dst[c] = s4[c];
            #pragma unroll
            for (int c=0;c<4;++c)
                #pragma unroll
                for (int e=0;e<4;++e){
                    dst[4 + c*8 + 2*e    ] = acc2[c][e][0];
                    dst[4 + c*8 + 2*e + 1] = acc2[c][e][1];
                }
        }
        __syncthreads();
        if (ig == 0){
            const float* src = sBuf + (size_t)t*37;
            #pragma unroll
            for (int c=0;c<4;++c) s4[c] += src[c];
            #pragma unroll
            for (int c=0;c<4;++c)
                #pragma unroll
                for (int e=0;e<4;++e){
                    acc2[c][e][0] += src[4 + c*8 + 2*e    ];
                    acc2[c][e][1] += src[4 + c*8 + 2*e + 1];
                }
        }
    }

    size_t bp = ((size_t)b*128 + jt)*SPLIT + sp;

    __syncthreads();
    #pragma unroll
    for (int k=0;k<4;++k) sBuf[(il_w*8 + jl_w)*4 + k] = Tp[k];
    __syncthreads();
    if (t < 8){
        float T0=0,T1=0,T2=0,T3=0;
        for (int s2=0;s2<32;++s2){
            const float* p = sBuf + (s2*8+t)*4;
            T0+=p[0];T1+=p[1];T2+=p[2];T3+=p[3];
        }
        float* td = Tws + (bp*8 + t)*4;
        td[0]=T0; td[1]=T1; td[2]=T2; td[3]=T3;
    }

    if (ig == 0){
        if (dq == 0){
            #pragma unroll
            for (int c=0;c<4;++c)
                Sws[bp*32 + h*8 + jh*4 + c] = s4[c];
        }
        #pragma unroll
        for (int c=0;c<4;++c){
            float* dst = Pws + (((size_t)bp*8 + jh*4 + c)*32 + h*8 + dq)*8;
            float4* d4 = reinterpret_cast<float4*>(dst);
            d4[0] = make_float4(acc2[c][0][0],acc2[c][0][1],acc2[c][1][0],acc2[c][1][1]);
            d4[1] = make_float4(acc2[c][2][0],acc2[c][2][1],acc2[c][3][0],acc2[c][3][1]);
        }
    }
}

// ---- kernel 4: merge split partials, normalize, add gelu(g)@W_fcg ----
template<int SPLIT>
__global__ __launch_bounds__(256) void k_merge(
    const float* __restrict__ Pws, const float* __restrict__ Sws,
    const float* __restrict__ Tws,
    const float* __restrict__ Gd_ws, const float* __restrict__ cnt_ws,
    const float* __restrict__ W_ffn, const float* __restrict__ W_fcg,
    const float* __restrict__ b_fcg, float* __restrict__ out)
{
    int b  = blockIdx.x >> 7;
    int jt = blockIdx.x & 127;
    int j0 = jt*8;
    int t  = threadIdx.x;
    int jl = t >> 5, hd = t & 31, h = hd >> 3, dq = hd & 7;
    __shared__ float sG[8][8];

    size_t bp0 = ((size_t)b*128 + jt)*SPLIT;
    float s = 0.0f, acc[8] = {0,0,0,0,0,0,0,0};
    #pragma unroll
    for (int sp2=0; sp2<SPLIT; ++sp2){
        const float* p = Pws + ((bp0+sp2)*256 + t)*8;
        float4 p0 = *reinterpret_cast<const float4*>(p);
        float4 p1 = *reinterpret_cast<const float4*>(p+4);
        acc[0]+=p0.x; acc[1]+=p0.y; acc[2]+=p0.z; acc[3]+=p0.w;
        acc[4]+=p1.x; acc[5]+=p1.y; acc[6]+=p1.z; acc[7]+=p1.w;
        s += Sws[(bp0+sp2)*32 + h*8 + jl];
    }
    if (t < 8){
        float T[4] = {0,0,0,0};
        #pragma unroll
        for (int sp2=0; sp2<SPLIT; ++sp2){
            const float* tp = Tws + ((bp0+sp2)*8 + t)*4;
            #pragma unroll
            for (int k=0;k<4;++k) T[k]+=tp[k];
        }
        size_t cj = (size_t)b*1024 + j0 + t;
        float cf = cnt_ws[cj];
        float inv = __fdividef(1.0f, cf + 1.0f);
        #pragma unroll
        for (int kk=0;kk<8;++kk){
            float a = cf*Gd_ws[cj*8+kk];
            #pragma unroll
            for (int k=0;k<4;++k) a += T[k]*W_ffn[k*8+kk];
            sG[t][kk] = gelu_f(a*inv);
        }
    }
    __syncthreads();

    float rs = (s > 0.0f) ? (1.0f/s) : 0.0f;
    int col0 = h*64 + dq*8;
    float gg[8];
    #pragma unroll
    for (int kk=0;kk<8;++kk) gg[kk]=sG[jl][kk];
    float o[8];
    #pragma unroll
    for (int d2=0;d2<8;++d2){
        float a = b_fcg[col0+d2];
        #pragma unroll
        for (int kk=0;kk<8;++kk) a += gg[kk]*W_fcg[kk*256 + col0 + d2];
        o[d2] = acc[d2]*rs + a;
    }
    float* ob = out + ((size_t)b*1024 + j0 + jl)*256 + col0;
    float4* o4 = reinterpret_cast<float4*>(ob);
    o4[0] = make_float4(o[0],o[1],o[2],o[3]);
    o4[1] = make_float4(o[4],o[5],o[6],o[7]);
}

extern "C" void kernel_launch(void* const* d_in, const int* in_sizes, int n_in,
                              void* d_out, int out_size, void* d_ws, size_t ws_size,
                              hipStream_t stream)
{
    const float* prev  = (const float*)d_in[0];
    const float* curr  = (const float*)d_in[1];
    const int*   edges = (const int*)  d_in[2];
    const float* W_pre = (const float*)d_in[3];
    const float* b_pre = (const float*)d_in[4];
    const float* W_cur = (const float*)d_in[5];
    const float* b_cur = (const float*)d_in[6];
    const float* W_fuse= (const float*)d_in[7];
    const float* b_fuse= (const float*)d_in[8];
    const float* W_ffn = (const float*)d_in[9];
    const float* b_ffn = (const float*)d_in[10];
    const float* W_fcc = (const float*)d_in[11];
    const float* b_fcc = (const float*)d_in[12];
    const float* W_fcg = (const float*)d_in[13];
    const float* b_fcg = (const float*)d_in[14];
    float* out = (float*)d_out;

    float* u_ws   = (float*)d_ws;          // 16384 floats
    float* v_ws   = u_ws  + 16384;         // 16384
    float* Gd_ws  = v_ws  + 16384;         // 32768
    float* cnt_ws = Gd_ws + 32768;         // 4096
    float* Pws    = cnt_ws + 4096;
    const size_t base_f = 16384 + 16384 + 32768 + 4096;

    k_rows<<<dim3(2048), dim3(256), 0, stream>>>(prev, curr, W_pre, b_pre,
        W_cur, b_cur, W_fuse, b_fuse, u_ws, v_ws);
    k_cols<<<dim3(256), dim3(256), 0, stream>>>(edges, u_ws, v_ws,
        W_ffn, b_ffn, Gd_ws, cnt_ws);

    const size_t p4 = (size_t)4*128*4*256*8, s4v = (size_t)4*128*4*32,
                 t4 = (size_t)4*128*4*8*4;
    const size_t wW_full = (size_t)4*1024*1024*4;       // 16.78M floats
    const size_t wW_b    = wW_full/4;                   // per-batch
    const size_t part_f  = base_f + p4 + s4v + t4;
    const size_t need_t1 = (part_f + wW_full) * 4;
    const size_t need_t2 = (part_f + wW_b) * 4;
    const size_t p2 = p4/2, s2v = s4v/2, t2 = t4/2;
    const size_t need_f4 = part_f * 4;
    const size_t need_f2 = (base_f + p2 + s2v + t2) * 4;

    float* Sws = Pws + p4;
    float* Tws = Sws + s4v;
    float* wWp = Tws + t4;

    if (ws_size >= need_t1){
        k_logit<4><<<dim3(2048), dim3(256), 0, stream>>>(edges, u_ws, v_ws,
            Gd_ws, W_ffn, W_fcc, b_fcc, wWp, Tws, 0);
        k_pv<4><<<dim3(2048), dim3(256), 0, stream>>>(prev, wWp, Pws, Sws, 0);
        k_merge<4><<<dim3(512), dim3(256), 0, stream>>>(Pws, Sws, Tws, Gd_ws,
            cnt_ws, W_ffn, W_fcg, b_fcg, out);
    } else if (ws_size >= need_t2){
        for (int bb = 0; bb < 4; ++bb){
            k_logit<4><<<dim3(512), dim3(256), 0, stream>>>(edges, u_ws, v_ws,
                Gd_ws, W_ffn, W_fcc, b_fcc, wWp, Tws, bb);
            k_pv<4><<<dim3(512), dim3(256), 0, stream>>>(prev, wWp, Pws, Sws, bb);
        }
        k_merge<4><<<dim3(512), dim3(256), 0, stream>>>(Pws, Sws, Tws, Gd_ws,
            cnt_ws, W_ffn, W_fcg, b_fcg, out);
    } else if (ws_size >= need_f4){
        k_main<4><<<dim3(2048), dim3(256), 0, stream>>>(prev, edges, u_ws, v_ws,
            Gd_ws, W_ffn, W_fcc, b_fcc, Pws, Sws, Tws);
        k_merge<4><<<dim3(512), dim3(256), 0, stream>>>(Pws, Sws, Tws, Gd_ws,
            cnt_ws, W_ffn, W_fcg, b_fcg, out);
    } else if (ws_size >= need_f2){
        float* Sws2 = Pws + p2;
        float* Tws2 = Sws2 + s2v;
        k_main<2><<<dim3(1024), dim3(256), 0, stream>>>(prev, edges, u_ws, v_ws,
            Gd_ws, W_ffn, W_fcc, b_fcc, Pws, Sws2, Tws2);
        k_merge<2><<<dim3(512), dim3(256), 0, stream>>>(Pws, Sws2, Tws2, Gd_ws,
            cnt_ws, W_ffn, W_fcg, b_fcg, out);
    } else {
        const size_t p1 = p4/4, s1 = s4v/4;
        float* Sws1 = Pws + p1;
        float* Tws1 = Sws1 + s1;
        k_main<1><<<dim3(512), dim3(256), 0, stream>>>(prev, edges, u_ws, v_ws,
            Gd_ws, W_ffn, W_fcc, b_fcc, Pws, Sws1, Tws1);
        k_merge<1><<<dim3(512), dim3(256), 0, stream>>>(Pws, Sws1, Tws1, Gd_ws,
            cnt_ws, W_ffn, W_fcg, b_fcg, out);
    }
}

// Round 14
// 129.667 us; speedup vs baseline: 1.1245x; 1.1245x over previous
//
#include <hip/hip_runtime.h>

// ---------------------------------------------------------------------------
// B=4, N1=1024, N2=1024, D=256, H=4, Dh=64
//   u[b,i,4] = gelu(prev@W_pre+b_pre) @ W_fuse[0:6]
//   v[b,j,4] = gelu(curr@W_cur+b_cur) @ W_fuse[6:12] + b_fuse
//   c = mask ? u_i+v_j : 0
//   Gd_j[8] = gelu(d_j)@W_ffn[4:8] + gelu(e_j)@W_ffn[8:12] + b_ffn
//   logits = gelu(gelu(c)@W_ffn[0:4] + Gd_j)@W_fcc + b_fcc
//   softmax over i WITHOUT max-subtraction (masked -> w=0); plain-sum partials
//   res = P @ prev (per-head);  g_j = (T_j@W_ffn[0:4]+cnt*Gd_j)/(cnt+1)
//   out = res + gelu(g)@W_fcg + b_fcg
// Round-13 lesson: global-w split FAILED (145us; k_pv 82us @ 21% VALU).
//   PV dominates and is L2-latency/BW-bound on prev re-reads (128 jt-blocks
//   x 4MB = 512MB L2). Fix: jtile=16 fused -> halves prev L2 traffic, keeps
//   round-12 compaction/exp-at-write/plain-sum machinery.
// Round-9 lesson: exp once at w-write. Round-7: balance cols/thread vs VMEM.
// Round-6: denominators are PER (column, HEAD). Round-5: >128 VGPR cliff.
// Round-4: never cap __launch_bounds__ min-waves (spill -> HBM).
// ---------------------------------------------------------------------------

typedef float v2f __attribute__((ext_vector_type(2)));
__device__ __forceinline__ v2f pk_fma(v2f a, v2f b, v2f c){
    return __builtin_elementwise_fma(a, b, c);
}

__device__ __forceinline__ float gelu_f(float x){
    float x2 = x*x;
    float tt = x * __builtin_fmaf(0.044715f, x2, 1.0f);   // x + 0.044715 x^3
    float e  = exp2f(2.3022082f * tt);                    // exp(1.59576912*tt)
    return x - __fdividef(x, e + 1.0f);
}

// ---- kernel 1: per-row u (prev side) and v (curr side), one wave per row ----
__global__ __launch_bounds__(256) void k_rows(
    const float* __restrict__ prev, const float* __restrict__ curr,
    const float* __restrict__ W_pre, const float* __restrict__ b_pre,
    const float* __restrict__ W_cur, const float* __restrict__ b_cur,
    const float* __restrict__ W_fuse, const float* __restrict__ b_fuse,
    float* __restrict__ u_ws, float* __restrict__ v_ws)
{
    int gid  = blockIdx.x * 256 + threadIdx.x;
    int wave = gid >> 6;
    int lane = threadIdx.x & 63;
    bool isPrev = wave < 4096;
    int row = isPrev ? wave : (wave - 4096);
    const float* xrow = (isPrev ? prev : curr) + (size_t)row * 256;
    const float* W  = isPrev ? W_pre : W_cur;
    const float* bv = isPrev ? b_pre : b_cur;

    float4 x4 = *reinterpret_cast<const float4*>(xrow + lane*4);
    const float* Wl = W + lane*24;
    float p[6];
    #pragma unroll
    for (int k=0;k<6;++k)
        p[k] = x4.x*Wl[k] + x4.y*Wl[6+k] + x4.z*Wl[12+k] + x4.w*Wl[18+k];
    #pragma unroll
    for (int off=32; off>=1; off>>=1){
        #pragma unroll
        for (int k=0;k<6;++k) p[k] += __shfl_xor(p[k], off, 64);
    }
    if (lane == 0){
        float g[6];
        #pragma unroll
        for(int k=0;k<6;++k) g[k] = gelu_f(p[k] + bv[k]);
        int rb = isPrev ? 0 : 6;
        float o[4];
        #pragma unroll
        for(int kk=0;kk<4;++kk){
            float a = isPrev ? 0.0f : b_fuse[kk];
            #pragma unroll
            for(int k=0;k<6;++k) a += g[k]*W_fuse[(rb+k)*4+kk];
            o[kk]=a;
        }
        float* dst = (isPrev ? u_ws : v_ws) + (size_t)row*4;
        *reinterpret_cast<float4*>(dst) = make_float4(o[0],o[1],o[2],o[3]);
    }
}

// ---- kernel 2: per-column reductions over edges + Gd precompute ----
__global__ __launch_bounds__(256) void k_cols(
    const int* __restrict__ edges,
    const float* __restrict__ u_ws, const float* __restrict__ v_ws,
    const float* __restrict__ W_ffn, const float* __restrict__ b_ffn,
    float* __restrict__ Gd_ws, float* __restrict__ cnt_ws)
{
    int b  = blockIdx.x >> 6;
    int j0 = (blockIdx.x & 63) * 16;
    int t  = threadIdx.x;
    int jq = t & 3, sl = t >> 2;
    const int*   eb = edges + (size_t)b*1048576 + j0 + jq*4;
    const float* ub = u_ws + (size_t)b*4096;

    int   cnt[4] = {0,0,0,0};
    float S[4][4] = {{0.f}};
    float M[4][4];
    #pragma unroll
    for (int q=0;q<4;++q)
        #pragma unroll
        for (int k=0;k<4;++k) M[q][k] = -3.4e38f;

    #pragma unroll 4
    for (int ii=0; ii<16; ++ii){
        int i = sl*16 + ii;
        int4   e4 = *reinterpret_cast<const int4*>(eb + (size_t)i*1024);
        float4 u4 = *reinterpret_cast<const float4*>(ub + i*4);
        float uu[4] = {u4.x,u4.y,u4.z,u4.w};
        int   ee[4] = {e4.x,e4.y,e4.z,e4.w};
        #pragma unroll
        for (int q=0;q<4;++q){
            bool mk = ee[q]!=0;
            cnt[q] += mk ? 1 : 0;
            #pragma unroll
            for (int k=0;k<4;++k){
                S[q][k] += mk ? uu[k] : 0.0f;
                M[q][k]  = mk ? fmaxf(M[q][k],uu[k]) : M[q][k];
            }
        }
    }
    __shared__ float rS[64][16][4];
    __shared__ float rM[64][16][4];
    __shared__ int   rC[64][16];
    #pragma unroll
    for (int q=0;q<4;++q){
        int c = jq*4+q;
        #pragma unroll
        for (int k=0;k<4;++k){ rS[sl][c][k]=S[q][k]; rM[sl][c][k]=M[q][k]; }
        rC[sl][c]=cnt[q];
    }
    __syncthreads();
    float aS[4], aM[4]; int aC=0; int c2=0, hf=0;
    if (t < 128){
        c2 = t & 15; hf = t >> 4;
        #pragma unroll
        for(int k=0;k<4;++k){ aS[k]=0.f; aM[k]=-3.4e38f; }
        for (int s2=hf*8; s2<hf*8+8; ++s2){
            aC += rC[s2][c2];
            #pragma unroll
            for(int k=0;k<4;++k){ aS[k]+=rS[s2][c2][k]; aM[k]=fmaxf(aM[k],rM[s2][c2][k]); }
        }
    }
    __syncthreads();
    if (t < 128){
        rC[hf][c2]=aC;
        #pragma unroll
        for(int k=0;k<4;++k){ rS[hf][c2][k]=aS[k]; rM[hf][c2][k]=aM[k]; }
    }
    __syncthreads();
    if (t < 16){
        int cc=0; float Sa[4]={0,0,0,0};
        float Ma[4]={-3.4e38f,-3.4e38f,-3.4e38f,-3.4e38f};
        for (int s2=0;s2<8;++s2){
            cc += rC[s2][t];
            #pragma unroll
            for(int k=0;k<4;++k){ Sa[k]+=rS[s2][t][k]; Ma[k]=fmaxf(Ma[k],rM[s2][t][k]); }
        }
        size_t cj = (size_t)b*1024 + j0 + t;
        float4 v4 = *reinterpret_cast<const float4*>(v_ws + cj*4);
        float vv[4]={v4.x,v4.y,v4.z,v4.w};
        float cf = (float)cc, e1 = cf + 1.0f;
        float gd[4], ge[4];
        #pragma unroll
        for(int k=0;k<4;++k){
            float dk = (Sa[k] + cf*vv[k]) / e1;
            float ek;
            if (cc == 0) ek = 0.0f;
            else { float m1 = Ma[k]+vv[k]; ek = (cc < 1024) ? fmaxf(m1, 0.0f) : m1; }
            gd[k]=gelu_f(dk); ge[k]=gelu_f(ek);
        }
        #pragma unroll
        for(int kk=0;kk<8;++kk){
            float a = b_ffn[kk];
            #pragma unroll
            for(int k=0;k<4;++k)
                a += gd[k]*W_ffn[(4+k)*8+kk] + ge[k]*W_ffn[(8+k)*8+kk];
            Gd_ws[cj*8+kk]=a;
        }
        cnt_ws[cj]=cf;
    }
}

// ---- kernel 3: jtile=16 fused, two-pass compacted logits + packed-FMA PV ----
// Block = (b, jtile of 16 cols, sp i-part). 256 threads, grid 4*64*SPLIT.
// Pass1 role: (il_w=t>>4 in 0..16, jl_w=t&15); rows il_w+16r, r<4.
// PV role:    (jg=t&3, h=(t>>2)&3, dq=(t>>4)&7, ig=t>>7): 4 cols x 8 dims,
//             rows ig*32..+32 per chunk. acc2[4][4]; 2-way tail ig-merge.
template<int SPLIT>
__global__ __launch_bounds__(256) void k_main16(
    const float* __restrict__ prev, const int* __restrict__ edges,
    const float* __restrict__ u_ws, const float* __restrict__ v_ws,
    const float* __restrict__ Gd_ws,
    const float* __restrict__ W_ffn, const float* __restrict__ W_fcc,
    const float* __restrict__ b_fcc,
    float* __restrict__ Pws, float* __restrict__ Sws, float* __restrict__ Tws)
{
    const int RPB = 1024/SPLIT;
    int bid = blockIdx.x;
    int sp  = bid & (SPLIT-1);
    int jt  = (bid / SPLIT) & 63;
    int b   = bid / (SPLIT*64);
    int j0  = jt*16;
    int t   = threadIdx.x;
    int lane = t & 63;
    int wv   = t >> 6;
    int jl_w = t & 15, il_w = t >> 4;
    int jg = t & 3, h = (t >> 2) & 3, dq = (t >> 4) & 7, ig = t >> 7;

    __shared__ __align__(16) float sBuf[4736];   // sLog 64*68 / merge 128*37 / sT
    __shared__ __align__(16) float sU[64][4];
    __shared__ __align__(16) float sV[16][4];
    __shared__ __align__(16) float sGd[16][8];
    __shared__ __align__(16) float sGc[1024][4];
    __shared__ unsigned short sPairs[1024];
    __shared__ unsigned long long sBal[16];
    float* sLog = sBuf;

    if (t < 64)  (&sV[0][0])[t]  = v_ws[((size_t)b*1024 + j0)*4 + t];
    if (t < 128) (&sGd[0][0])[t] = Gd_ws[((size_t)b*1024 + j0)*8 + t];

    const float LOG2E = 1.4426950408889634f;
    float W4r[4][8], Wfc[8][4], bfc[4];
    #pragma unroll
    for(int k=0;k<4;++k)
        #pragma unroll
        for(int kk=0;kk<8;++kk) W4r[k][kk]=W_ffn[k*8+kk];
    #pragma unroll
    for(int kk=0;kk<8;++kk)
        #pragma unroll
        for(int hh=0;hh<4;++hh) Wfc[kk][hh]=W_fcc[kk*4+hh]*LOG2E;
    #pragma unroll
    for(int hh=0;hh<4;++hh) bfc[hh]=b_fcc[hh]*LOG2E;

    v2f sA = {0,0}, sB = {0,0};
    v2f acc2[4][4];
    #pragma unroll
    for (int c=0;c<4;++c)
        #pragma unroll
        for (int e=0;e<4;++e) acc2[c][e] = (v2f){0.f,0.f};
    float Tp[4] = {0,0,0,0};

    const int*   ebase  = edges + (size_t)b*1048576 + j0;
    const float* pbBase = prev  + (size_t)b*262144 + h*64 + dq*8;

    const int NCH = RPB/64;
    const int base_i0 = sp*RPB;

    __syncthreads();                              // sV/sGd visible
    float4 v4p = *reinterpret_cast<const float4*>(&sV[jl_w][0]);

    // ---- prologue prefetch for chunk 0 ----
    float su_r = u_ws[((size_t)b*1024 + base_i0)*4 + t];
    int egr[4];
    #pragma unroll
    for (int r=0;r<4;++r)
        egr[r] = ebase[(size_t)(base_i0 + il_w + 16*r)*1024 + jl_w];

    unsigned long long lm = (1ull << lane) - 1ull;

    for (int cc=0; cc<NCH; ++cc){
        int i0 = base_i0 + cc*64;
        (&sU[0][0])[t] = su_r;                    // publish prefetched sU
        __syncthreads();                          // B1: sU visible, PV done

        // ---- pass 1: gc for all pairs -> Tp + sGc; zero sLog; ballots ----
        unsigned long long bls[4];
        #pragma unroll
        for (int r=0;r<4;++r){
            int row = il_w + 16*r;
            int eg = egr[r];
            float4 u4 = *reinterpret_cast<const float4*>(&sU[row][0]);
            float g0 = gelu_f(u4.x + v4p.x);
            float g1 = gelu_f(u4.y + v4p.y);
            float g2 = gelu_f(u4.z + v4p.z);
            float g3 = gelu_f(u4.w + v4p.w);
            Tp[0] += eg ? g0 : 0.0f;
            Tp[1] += eg ? g1 : 0.0f;
            Tp[2] += eg ? g2 : 0.0f;
            Tp[3] += eg ? g3 : 0.0f;
            int pid = row*16 + jl_w;
            *reinterpret_cast<float4*>(&sGc[pid][0]) = make_float4(g0,g1,g2,g3);
            sLog[row*68 +  0 + jl_w] = 0.0f;
            sLog[row*68 + 16 + jl_w] = 0.0f;
            sLog[row*68 + 32 + jl_w] = 0.0f;
            sLog[row*68 + 48 + jl_w] = 0.0f;
            bls[r] = __ballot(eg != 0);
            if (lane == 0) sBal[r*4 + wv] = bls[r];
        }
        __syncthreads();                          // B2: sBal/zeros/sGc ready

        // ---- prefix sums -> compaction positions ----
        int bases[4] = {0,0,0,0};
        int total = 0;
        #pragma unroll
        for (int i2=0;i2<16;++i2){
            int c = __popcll(sBal[i2]);
            #pragma unroll
            for (int r=0;r<4;++r) if (i2 == r*4 + wv) bases[r] = total;
            total += c;
        }
        #pragma unroll
        for (int r=0;r<4;++r){
            if (egr[r]){
                int pos = bases[r] + (int)__popcll(bls[r] & lm);
                sPairs[pos] = (unsigned short)((il_w + 16*r)*16 + jl_w);
            }
        }

        // ---- prefetch next chunk ----
        {
            int i0n = base_i0 + ((cc+1 < NCH) ? (cc+1)*64 : 0);
            su_r = u_ws[((size_t)b*1024 + i0n)*4 + t];
            #pragma unroll
            for (int r=0;r<4;++r)
                egr[r] = ebase[(size_t)(i0n + il_w + 16*r)*1024 + jl_w];
        }
        __syncthreads();                          // B3: sPairs ready

        // ---- pass 2: fu chain + logits + exp2, active pairs only ----
        for (int p = t; p < total; p += 256){
            int pid = sPairs[p];
            int row = pid >> 4, jl = pid & 15;
            float4 gcv = *reinterpret_cast<const float4*>(&sGc[pid][0]);
            float4 gd0 = *reinterpret_cast<const float4*>(&sGd[jl][0]);
            float4 gd1 = *reinterpret_cast<const float4*>(&sGd[jl][4]);
            float gdv[8] = {gd0.x,gd0.y,gd0.z,gd0.w,gd1.x,gd1.y,gd1.z,gd1.w};
            float fu[8];
            #pragma unroll
            for (int kk=0;kk<8;++kk){
                float a = gdv[kk];
                a = __builtin_fmaf(gcv.x, W4r[0][kk], a);
                a = __builtin_fmaf(gcv.y, W4r[1][kk], a);
                a = __builtin_fmaf(gcv.z, W4r[2][kk], a);
                a = __builtin_fmaf(gcv.w, W4r[3][kk], a);
                fu[kk] = gelu_f(a);
            }
            #pragma unroll
            for (int hh=0;hh<4;++hh){
                float a = bfc[hh];
                #pragma unroll
                for (int kk=0;kk<8;++kk) a = __builtin_fmaf(fu[kk], Wfc[kk][hh], a);
                sLog[row*68 + hh*16 + jl] = exp2f(a);
            }
        }
        __syncthreads();                          // B4: sLog ready

        // ---- PV: rows ig*32..+32, cols jg*4..+4, dims h*64+dq*8..+8 ----
        const float* pc = pbBase + (size_t)(i0 + ig*32)*256;
        const float* lg = sLog + (ig*32)*68 + h*16 + jg*4;
        #pragma unroll 4
        for (int i=0;i<32;++i){
            float4 lv = *reinterpret_cast<const float4*>(lg + i*68);
            float4 a0 = *reinterpret_cast<const float4*>(pc + (size_t)i*256);
            float4 a1 = *reinterpret_cast<const float4*>(pc + (size_t)i*256 + 4);
            sA += (v2f){lv.x, lv.y};
            sB += (v2f){lv.z, lv.w};
            v2f p01 = {a0.x,a0.y}, p23 = {a0.z,a0.w};
            v2f p45 = {a1.x,a1.y}, p67 = {a1.z,a1.w};
            v2f w0 = {lv.x,lv.x}, w1 = {lv.y,lv.y};
            v2f w2 = {lv.z,lv.z}, w3 = {lv.w,lv.w};
            acc2[0][0]=pk_fma(w0,p01,acc2[0][0]); acc2[0][1]=pk_fma(w0,p23,acc2[0][1]);
            acc2[0][2]=pk_fma(w0,p45,acc2[0][2]); acc2[0][3]=pk_fma(w0,p67,acc2[0][3]);
            acc2[1][0]=pk_fma(w1,p01,acc2[1][0]); acc2[1][1]=pk_fma(w1,p23,acc2[1][1]);
            acc2[1][2]=pk_fma(w1,p45,acc2[1][2]); acc2[1][3]=pk_fma(w1,p67,acc2[1][3]);
            acc2[2][0]=pk_fma(w2,p01,acc2[2][0]); acc2[2][1]=pk_fma(w2,p23,acc2[2][1]);
            acc2[2][2]=pk_fma(w2,p45,acc2[2][2]); acc2[2][3]=pk_fma(w2,p67,acc2[2][3]);
            acc2[3][0]=pk_fma(w3,p01,acc2[3][0]); acc2[3][1]=pk_fma(w3,p23,acc2[3][1]);
            acc2[3][2]=pk_fma(w3,p45,acc2[3][2]); acc2[3][3]=pk_fma(w3,p67,acc2[3][3]);
        }
    }

    float s4[4] = {sA[0], sA[1], sB[0], sB[1]};

    // ---- 2-way tail ig-merge (plain sums), buffer 128*37 ----
    int r128 = t & 127;
    __syncthreads();
    if (ig == 1){
        float* dst = sBuf + (size_t)r128*37;
        #pragma unroll
        for (int c=0;c<4;++c) dst[c] = s4[c];
        #pragma unroll
        for (int c=0;c<4;++c)
            #pragma unroll
            for (int e=0;e<4;++e){
                dst[4 + c*8 + 2*e    ] = acc2[c][e][0];
                dst[4 + c*8 + 2*e + 1] = acc2[c][e][1];
            }
    }
    __syncthreads();
    if (ig == 0){
        const float* src = sBuf + (size_t)t*37;
        #pragma unroll
        for (int c=0;c<4;++c) s4[c] += src[c];
        #pragma unroll
        for (int c=0;c<4;++c)
            #pragma unroll
            for (int e=0;e<4;++e){
                acc2[c][e][0] += src[4 + c*8 + 2*e    ];
                acc2[c][e][1] += src[4 + c*8 + 2*e + 1];
            }
    }

    size_t bp = ((size_t)b*64 + jt)*SPLIT + sp;

    // ---- T reduction (sBuf reused; barrier separates from merge reads) ----
    __syncthreads();
    #pragma unroll
    for (int k=0;k<4;++k) sBuf[(il_w*16 + jl_w)*4 + k] = Tp[k];
    __syncthreads();
    if (t < 16){
        float T0=0,T1=0,T2=0,T3=0;
        for (int s2=0;s2<16;++s2){
            const float* p = sBuf + (s2*16+t)*4;
            T0+=p[0];T1+=p[1];T2+=p[2];T3+=p[3];
        }
        float* td = Tws + (bp*16 + t)*4;
        td[0]=T0; td[1]=T1; td[2]=T2; td[3]=T3;
    }

    // ---- partial outputs from ig==0 threads (t<128) ----
    if (ig == 0){
        if (dq == 0){                       // t<16: (jg,h)
            #pragma unroll
            for (int c=0;c<4;++c)
                Sws[bp*64 + h*16 + jg*4 + c] = s4[c];
        }
        #pragma unroll
        for (int c=0;c<4;++c){
            float* dst = Pws + (((size_t)bp*16 + jg*4 + c)*32 + h*8 + dq)*8;
            float4* d4 = reinterpret_cast<float4*>(dst);
            d4[0] = make_float4(acc2[c][0][0],acc2[c][0][1],acc2[c][1][0],acc2[c][1][1]);
            d4[1] = make_float4(acc2[c][2][0],acc2[c][2][1],acc2[c][3][0],acc2[c][3][1]);
        }
    }
}

// ---- kernel 4: merge split partials, normalize, add gelu(g)@W_fcg ----
// Block = (b, jt8 of 8 cols), grid 512; maps into jtile-16 partial layout.
template<int SPLIT>
__global__ __launch_bounds__(256) void k_merge16(
    const float* __restrict__ Pws, const float* __restrict__ Sws,
    const float* __restrict__ Tws,
    const float* __restrict__ Gd_ws, const float* __restrict__ cnt_ws,
    const float* __restrict__ W_ffn, const float* __restrict__ W_fcg,
    const float* __restrict__ b_fcg, float* __restrict__ out)
{
    int b   = blockIdx.x >> 7;
    int jt8 = blockIdx.x & 127;
    int jt16 = jt8 >> 1;
    int cb  = (jt8 & 1) * 8;
    int j0  = jt8*8;
    int t  = threadIdx.x;
    int jl = t >> 5, hd = t & 31, h = hd >> 3, dq = hd & 7;
    int col = cb + jl;
    __shared__ float sG[8][8];

    size_t bp0 = ((size_t)b*64 + jt16)*SPLIT;
    float s = 0.0f, acc[8] = {0,0,0,0,0,0,0,0};
    #pragma unroll
    for (int sp2=0; sp2<SPLIT; ++sp2){
        const float* p = Pws + (((bp0+sp2)*16 + col)*32 + hd)*8;
        float4 p0 = *reinterpret_cast<const float4*>(p);
        float4 p1 = *reinterpret_cast<const float4*>(p+4);
        acc[0]+=p0.x; acc[1]+=p0.y; acc[2]+=p0.z; acc[3]+=p0.w;
        acc[4]+=p1.x; acc[5]+=p1.y; acc[6]+=p1.z; acc[7]+=p1.w;
        s += Sws[(bp0+sp2)*64 + h*16 + col];
    }
    if (t < 8){
        float T[4] = {0,0,0,0};
        #pragma unroll
        for (int sp2=0; sp2<SPLIT; ++sp2){
            const float* tp = Tws + (((bp0+sp2)*16) + cb + t)*4;
            #pragma unroll
            for (int k=0;k<4;++k) T[k]+=tp[k];
        }
        size_t cj = (size_t)b*1024 + j0 + t;
        float cf = cnt_ws[cj];
        float inv = __fdividef(1.0f, cf + 1.0f);
        #pragma unroll
        for (int kk=0;kk<8;++kk){
            float a = cf*Gd_ws[cj*8+kk];
            #pragma unroll
            for (int k=0;k<4;++k) a += T[k]*W_ffn[k*8+kk];
            sG[t][kk] = gelu_f(a*inv);
        }
    }
    __syncthreads();

    float rs = (s > 0.0f) ? (1.0f/s) : 0.0f;
    int col0 = h*64 + dq*8;
    float gg[8];
    #pragma unroll
    for (int kk=0;kk<8;++kk) gg[kk]=sG[jl][kk];
    float o[8];
    #pragma unroll
    for (int d2=0;d2<8;++d2){
        float a = b_fcg[col0+d2];
        #pragma unroll
        for (int kk=0;kk<8;++kk) a += gg[kk]*W_fcg[kk*256 + col0 + d2];
        o[d2] = acc[d2]*rs + a;
    }
    float* ob = out + ((size_t)b*1024 + j0 + jl)*256 + col0;
    float4* o4 = reinterpret_cast<float4*>(ob);
    o4[0] = make_float4(o[0],o[1],o[2],o[3]);
    o4[1] = make_float4(o[4],o[5],o[6],o[7]);
}

extern "C" void kernel_launch(void* const* d_in, const int* in_sizes, int n_in,
                              void* d_out, int out_size, void* d_ws, size_t ws_size,
                              hipStream_t stream)
{
    const float* prev  = (const float*)d_in[0];
    const float* curr  = (const float*)d_in[1];
    const int*   edges = (const int*)  d_in[2];
    const float* W_pre = (const float*)d_in[3];
    const float* b_pre = (const float*)d_in[4];
    const float* W_cur = (const float*)d_in[5];
    const float* b_cur = (const float*)d_in[6];
    const float* W_fuse= (const float*)d_in[7];
    const float* b_fuse= (const float*)d_in[8];
    const float* W_ffn = (const float*)d_in[9];
    const float* b_ffn = (const float*)d_in[10];
    const float* W_fcc = (const float*)d_in[11];
    const float* b_fcc = (const float*)d_in[12];
    const float* W_fcg = (const float*)d_in[13];
    const float* b_fcg = (const float*)d_in[14];
    float* out = (float*)d_out;

    float* u_ws   = (float*)d_ws;          // 16384 floats
    float* v_ws   = u_ws  + 16384;         // 16384
    float* Gd_ws  = v_ws  + 16384;         // 32768
    float* cnt_ws = Gd_ws + 32768;         // 4096
    float* Pws    = cnt_ws + 4096;
    const size_t base_f = 16384 + 16384 + 32768 + 4096;

    k_rows<<<dim3(2048), dim3(256), 0, stream>>>(prev, curr, W_pre, b_pre,
        W_cur, b_cur, W_fuse, b_fuse, u_ws, v_ws);
    k_cols<<<dim3(256), dim3(256), 0, stream>>>(edges, u_ws, v_ws,
        W_ffn, b_ffn, Gd_ws, cnt_ws);

    // nblocks(SPLIT=4) = 4*64*4 = 1024; Pws 1024*16*32*8, Sws 1024*64,
    // Tws 1024*16*4 (same totals as round-12 p4/s4/t4).
    const size_t p4 = (size_t)1024*16*32*8;
    const size_t s4v = (size_t)1024*64;
    const size_t t4  = (size_t)1024*16*4;
    const size_t need4 = (base_f + p4 + s4v + t4) * 4;
    const size_t p2 = p4/2, s2v = s4v/2, t2 = t4/2;
    const size_t need2 = (base_f + p2 + s2v + t2) * 4;

    float* Sws = Pws + p4;
    float* Tws = Sws + s4v;

    if (ws_size >= need4){
        k_main16<4><<<dim3(1024), dim3(256), 0, stream>>>(prev, edges, u_ws,
            v_ws, Gd_ws, W_ffn, W_fcc, b_fcc, Pws, Sws, Tws);
        k_merge16<4><<<dim3(512), dim3(256), 0, stream>>>(Pws, Sws, Tws, Gd_ws,
            cnt_ws, W_ffn, W_fcg, b_fcg, out);
    } else if (ws_size >= need2){
        float* Sws2 = Pws + p2;
        float* Tws2 = Sws2 + s2v;
        k_main16<2><<<dim3(512), dim3(256), 0, stream>>>(prev, edges, u_ws,
            v_ws, Gd_ws, W_ffn, W_fcc, b_fcc, Pws, Sws2, Tws2);
        k_merge16<2><<<dim3(512), dim3(256), 0, stream>>>(Pws, Sws2, Tws2,
            Gd_ws, cnt_ws, W_ffn, W_fcg, b_fcg, out);
    } else {
        const size_t p1 = p4/4, s1 = s4v/4;
        float* Sws1 = Pws + p1;
        float* Tws1 = Sws1 + s1;
        k_main16<1><<<dim3(256), dim3(256), 0, stream>>>(prev, edges, u_ws,
            v_ws, Gd_ws, W_ffn, W_fcc, b_fcc, Pws, Sws1, Tws1);
        k_merge16<1><<<dim3(512), dim3(256), 0, stream>>>(Pws, Sws1, Tws1,
            Gd_ws, cnt_ws, W_ffn, W_fcg, b_fcg, out);
    }
}

// Round 15
// 125.191 us; speedup vs baseline: 1.1647x; 1.0358x over previous
//
#include <hip/hip_runtime.h>

// ---------------------------------------------------------------------------
// B=4, N1=1024, N2=1024, D=256, H=4, Dh=64
//   u[b,i,4] = gelu(prev@W_pre+b_pre) @ W_fuse[0:6]
//   v[b,j,4] = gelu(curr@W_cur+b_cur) @ W_fuse[6:12] + b_fuse
//   c = mask ? u_i+v_j : 0
//   Gd_j[8] = gelu(d_j)@W_ffn[4:8] + gelu(e_j)@W_ffn[8:12] + b_ffn
//   logits = gelu(gelu(c)@W_ffn[0:4] + Gd_j)@W_fcc + b_fcc
//   softmax over i WITHOUT max-subtraction (masked -> w=0); plain-sum partials
//   res = P @ prev (per-head);  g_j = (T_j@W_ffn[0:4]+cnt*Gd_j)/(cnt+1)
//   out = res + gelu(g)@W_fcg + b_fcg
// Round-14 lesson: jtile=16 (39KB LDS) cut occupancy 36->24, regressed.
//   Measured occupancy ~0.45x LDS-theoretical across rounds -> minimize LDS.
// Round-15: drop compaction (2.6us win, 9.3KB LDS cost), alias merge buffer
//   onto sLog -> ~10.9KB/block, 8 blocks/CU co-resident with grid 2048.
// Round-9 lesson: exp once at w-write. Round-7: balance cols/thread vs VMEM.
// Round-6: denominators are PER (column, HEAD). Round-5: >128 VGPR cliff
//   (and 64: waves/SIMD = 512/VGPR). Round-4: never cap min-waves.
// ---------------------------------------------------------------------------

typedef float v2f __attribute__((ext_vector_type(2)));
__device__ __forceinline__ v2f pk_fma(v2f a, v2f b, v2f c){
    return __builtin_elementwise_fma(a, b, c);
}

__device__ __forceinline__ float gelu_f(float x){
    float x2 = x*x;
    float tt = x * __builtin_fmaf(0.044715f, x2, 1.0f);   // x + 0.044715 x^3
    float e  = exp2f(2.3022082f * tt);                    // exp(1.59576912*tt)
    return x - __fdividef(x, e + 1.0f);
}

// ---- kernel 1: per-row u (prev side) and v (curr side), one wave per row ----
__global__ __launch_bounds__(256) void k_rows(
    const float* __restrict__ prev, const float* __restrict__ curr,
    const float* __restrict__ W_pre, const float* __restrict__ b_pre,
    const float* __restrict__ W_cur, const float* __restrict__ b_cur,
    const float* __restrict__ W_fuse, const float* __restrict__ b_fuse,
    float* __restrict__ u_ws, float* __restrict__ v_ws)
{
    int gid  = blockIdx.x * 256 + threadIdx.x;
    int wave = gid >> 6;
    int lane = threadIdx.x & 63;
    bool isPrev = wave < 4096;
    int row = isPrev ? wave : (wave - 4096);
    const float* xrow = (isPrev ? prev : curr) + (size_t)row * 256;
    const float* W  = isPrev ? W_pre : W_cur;
    const float* bv = isPrev ? b_pre : b_cur;

    float4 x4 = *reinterpret_cast<const float4*>(xrow + lane*4);
    const float* Wl = W + lane*24;
    float p[6];
    #pragma unroll
    for (int k=0;k<6;++k)
        p[k] = x4.x*Wl[k] + x4.y*Wl[6+k] + x4.z*Wl[12+k] + x4.w*Wl[18+k];
    #pragma unroll
    for (int off=32; off>=1; off>>=1){
        #pragma unroll
        for (int k=0;k<6;++k) p[k] += __shfl_xor(p[k], off, 64);
    }
    if (lane == 0){
        float g[6];
        #pragma unroll
        for(int k=0;k<6;++k) g[k] = gelu_f(p[k] + bv[k]);
        int rb = isPrev ? 0 : 6;
        float o[4];
        #pragma unroll
        for(int kk=0;kk<4;++kk){
            float a = isPrev ? 0.0f : b_fuse[kk];
            #pragma unroll
            for(int k=0;k<6;++k) a += g[k]*W_fuse[(rb+k)*4+kk];
            o[kk]=a;
        }
        float* dst = (isPrev ? u_ws : v_ws) + (size_t)row*4;
        *reinterpret_cast<float4*>(dst) = make_float4(o[0],o[1],o[2],o[3]);
    }
}

// ---- kernel 2: per-column reductions over edges + Gd precompute ----
__global__ __launch_bounds__(256) void k_cols(
    const int* __restrict__ edges,
    const float* __restrict__ u_ws, const float* __restrict__ v_ws,
    const float* __restrict__ W_ffn, const float* __restrict__ b_ffn,
    float* __restrict__ Gd_ws, float* __restrict__ cnt_ws)
{
    int b  = blockIdx.x >> 6;
    int j0 = (blockIdx.x & 63) * 16;
    int t  = threadIdx.x;
    int jq = t & 3, sl = t >> 2;
    const int*   eb = edges + (size_t)b*1048576 + j0 + jq*4;
    const float* ub = u_ws + (size_t)b*4096;

    int   cnt[4] = {0,0,0,0};
    float S[4][4] = {{0.f}};
    float M[4][4];
    #pragma unroll
    for (int q=0;q<4;++q)
        #pragma unroll
        for (int k=0;k<4;++k) M[q][k] = -3.4e38f;

    #pragma unroll 4
    for (int ii=0; ii<16; ++ii){
        int i = sl*16 + ii;
        int4   e4 = *reinterpret_cast<const int4*>(eb + (size_t)i*1024);
        float4 u4 = *reinterpret_cast<const float4*>(ub + i*4);
        float uu[4] = {u4.x,u4.y,u4.z,u4.w};
        int   ee[4] = {e4.x,e4.y,e4.z,e4.w};
        #pragma unroll
        for (int q=0;q<4;++q){
            bool mk = ee[q]!=0;
            cnt[q] += mk ? 1 : 0;
            #pragma unroll
            for (int k=0;k<4;++k){
                S[q][k] += mk ? uu[k] : 0.0f;
                M[q][k]  = mk ? fmaxf(M[q][k],uu[k]) : M[q][k];
            }
        }
    }
    __shared__ float rS[64][16][4];
    __shared__ float rM[64][16][4];
    __shared__ int   rC[64][16];
    #pragma unroll
    for (int q=0;q<4;++q){
        int c = jq*4+q;
        #pragma unroll
        for (int k=0;k<4;++k){ rS[sl][c][k]=S[q][k]; rM[sl][c][k]=M[q][k]; }
        rC[sl][c]=cnt[q];
    }
    __syncthreads();
    float aS[4], aM[4]; int aC=0; int c2=0, hf=0;
    if (t < 128){
        c2 = t & 15; hf = t >> 4;
        #pragma unroll
        for(int k=0;k<4;++k){ aS[k]=0.f; aM[k]=-3.4e38f; }
        for (int s2=hf*8; s2<hf*8+8; ++s2){
            aC += rC[s2][c2];
            #pragma unroll
            for(int k=0;k<4;++k){ aS[k]+=rS[s2][c2][k]; aM[k]=fmaxf(aM[k],rM[s2][c2][k]); }
        }
    }
    __syncthreads();
    if (t < 128){
        rC[hf][c2]=aC;
        #pragma unroll
        for(int k=0;k<4;++k){ rS[hf][c2][k]=aS[k]; rM[hf][c2][k]=aM[k]; }
    }
    __syncthreads();
    if (t < 16){
        int cc=0; float Sa[4]={0,0,0,0};
        float Ma[4]={-3.4e38f,-3.4e38f,-3.4e38f,-3.4e38f};
        for (int s2=0;s2<8;++s2){
            cc += rC[s2][t];
            #pragma unroll
            for(int k=0;k<4;++k){ Sa[k]+=rS[s2][t][k]; Ma[k]=fmaxf(Ma[k],rM[s2][t][k]); }
        }
        size_t cj = (size_t)b*1024 + j0 + t;
        float4 v4 = *reinterpret_cast<const float4*>(v_ws + cj*4);
        float vv[4]={v4.x,v4.y,v4.z,v4.w};
        float cf = (float)cc, e1 = cf + 1.0f;
        float gd[4], ge[4];
        #pragma unroll
        for(int k=0;k<4;++k){
            float dk = (Sa[k] + cf*vv[k]) / e1;
            float ek;
            if (cc == 0) ek = 0.0f;
            else { float m1 = Ma[k]+vv[k]; ek = (cc < 1024) ? fmaxf(m1, 0.0f) : m1; }
            gd[k]=gelu_f(dk); ge[k]=gelu_f(ek);
        }
        #pragma unroll
        for(int kk=0;kk<8;++kk){
            float a = b_ffn[kk];
            #pragma unroll
            for(int k=0;k<4;++k)
                a += gd[k]*W_ffn[(4+k)*8+kk] + ge[k]*W_ffn[(8+k)*8+kk];
            Gd_ws[cj*8+kk]=a;
        }
        cnt_ws[cj]=cf;
    }
}

// ---- kernel 3: minimal-LDS single-pass logits + packed-FMA PV ----
// Block = (b, jtile of 8 cols, sp i-part). 256 threads, grid 4*128*SPLIT.
// Logit role: (il_w=t>>3 in 0..31, jl_w=t&7) -> writes w=exp2(logit*log2e).
// PV role:    (jh=t&1, h=(t>>1)&3, dq=(t>>3)&7, ig=t>>6): 4 cols x 8 dims,
//             rows ig*16..+16 per chunk. acc2[4][4]; single-buffer tail merge.
// LDS ~10.9KB -> 8 blocks/CU co-resident (vs round-12's 20.5KB / ~7).
template<int SPLIT>
__global__ __launch_bounds__(256) void k_main(
    const float* __restrict__ prev, const int* __restrict__ edges,
    const float* __restrict__ u_ws, const float* __restrict__ v_ws,
    const float* __restrict__ Gd_ws,
    const float* __restrict__ W_ffn, const float* __restrict__ W_fcc,
    const float* __restrict__ b_fcc,
    float* __restrict__ Pws, float* __restrict__ Sws, float* __restrict__ Tws)
{
    int bid = blockIdx.x;
    int sp  = bid & (SPLIT-1);
    int jt  = (bid / SPLIT) & 127;
    int b   = bid / (SPLIT*128);
    int j0  = jt*8;
    int t   = threadIdx.x;
    int jl_w = t & 7, il_w = t >> 3;
    int jh = t & 1, h = (t >> 1) & 3, dq = (t >> 3) & 7, ig = t >> 6;

    __shared__ __align__(16) float sBuf[2368]; // sLog 64*36 / merge 64*37 / sT
    __shared__ __align__(16) float sU[64][4];
    __shared__ __align__(16) float sV[8][4];
    __shared__ __align__(16) float sGd[8][8];
    float* sLog = sBuf;

    if (t < 32) (&sV[0][0])[t]  = v_ws[((size_t)b*1024 + j0)*4 + t];
    if (t < 64) (&sGd[0][0])[t] = Gd_ws[((size_t)b*1024 + j0)*8 + t];

    // uniform weights -> scalar regs; fold log2(e) into the final linear layer
    const float LOG2E = 1.4426950408889634f;
    float W4r[4][8], Wfc[8][4], bfc[4];
    #pragma unroll
    for(int k=0;k<4;++k)
        #pragma unroll
        for(int kk=0;kk<8;++kk) W4r[k][kk]=W_ffn[k*8+kk];
    #pragma unroll
    for(int kk=0;kk<8;++kk)
        #pragma unroll
        for(int hh=0;hh<4;++hh) Wfc[kk][hh]=W_fcc[kk*4+hh]*LOG2E;
    #pragma unroll
    for(int hh=0;hh<4;++hh) bfc[hh]=b_fcc[hh]*LOG2E;

    v2f sA = {0,0}, sB = {0,0};
    v2f acc2[4][4];
    #pragma unroll
    for (int c=0;c<4;++c)
        #pragma unroll
        for (int e=0;e<4;++e) acc2[c][e] = (v2f){0.f,0.f};
    float Tp[4] = {0,0,0,0};

    const int*   ebase  = edges + (size_t)b*1048576 + j0;
    const float* pbBase = prev  + (size_t)b*262144 + h*64 + dq*8;

    const int NCH = 16/SPLIT;
    const int base_i0 = sp*(1024/SPLIT);

    __syncthreads();                              // sV/sGd visible
    float4 v4p = *reinterpret_cast<const float4*>(&sV[jl_w][0]);
    float4 gd0 = *reinterpret_cast<const float4*>(&sGd[jl_w][0]);
    float4 gd1 = *reinterpret_cast<const float4*>(&sGd[jl_w][4]);

    // ---- prologue prefetch for chunk 0 ----
    float su_r = u_ws[((size_t)b*1024 + base_i0)*4 + t];
    int   egr0 = ebase[(size_t)(base_i0+il_w   )*1024 + jl_w];
    int   egr1 = ebase[(size_t)(base_i0+il_w+32)*1024 + jl_w];

    for (int cc=0; cc<NCH; ++cc){
        int i0 = base_i0 + cc*64;
        (&sU[0][0])[t] = su_r;                   // publish prefetched sU
        __syncthreads();                         // B1: sU visible; PV done

        // ---- logit phase: 512 pairs, 2 per thread; store w = exp2(...) ----
        int eg2[2] = {egr0, egr1};
        #pragma unroll
        for (int r=0;r<2;++r){
            int il = il_w + 32*r;
            int eg = eg2[r];
            float4 u4 = *reinterpret_cast<const float4*>(&sU[il][0]);
            float g0 = gelu_f(u4.x + v4p.x);
            float g1 = gelu_f(u4.y + v4p.y);
            float g2 = gelu_f(u4.z + v4p.z);
            float g3 = gelu_f(u4.w + v4p.w);
            Tp[0] += eg ? g0 : 0.0f;
            Tp[1] += eg ? g1 : 0.0f;
            Tp[2] += eg ? g2 : 0.0f;
            Tp[3] += eg ? g3 : 0.0f;
            float gdv[8] = {gd0.x,gd0.y,gd0.z,gd0.w,gd1.x,gd1.y,gd1.z,gd1.w};
            float fu[8];
            #pragma unroll
            for(int kk=0;kk<8;++kk){
                float a = gdv[kk];
                a = __builtin_fmaf(g0, W4r[0][kk], a);
                a = __builtin_fmaf(g1, W4r[1][kk], a);
                a = __builtin_fmaf(g2, W4r[2][kk], a);
                a = __builtin_fmaf(g3, W4r[3][kk], a);
                fu[kk] = gelu_f(a);
            }
            #pragma unroll
            for(int hh=0;hh<4;++hh){
                float a = bfc[hh];
                #pragma unroll
                for(int kk=0;kk<8;++kk) a = __builtin_fmaf(fu[kk], Wfc[kk][hh], a);
                sLog[il*36 + hh*8 + jl_w] = eg ? exp2f(a) : 0.0f;
            }
        }

        // ---- prefetch next chunk (latency hidden under barrier + PV) ----
        {
            int i0n = base_i0 + ((cc+1 < NCH) ? (cc+1)*64 : 0);
            su_r = u_ws[((size_t)b*1024 + i0n)*4 + t];
            egr0 = ebase[(size_t)(i0n+il_w   )*1024 + jl_w];
            egr1 = ebase[(size_t)(i0n+il_w+32)*1024 + jl_w];
        }
        __syncthreads();                         // B2: sLog ready

        // ---- PV (packed fp32): rows ig*16..+16, cols jh*4..+4, 8 dims ----
        const float* pc = pbBase + (size_t)(i0 + ig*16)*256;
        const float* lg = sLog + (ig*16)*36 + h*8 + jh*4;
        #pragma unroll 4
        for (int i=0;i<16;++i){
            float4 lv = *reinterpret_cast<const float4*>(lg + i*36);
            float4 a0 = *reinterpret_cast<const float4*>(pc + (size_t)i*256);
            float4 a1 = *reinterpret_cast<const float4*>(pc + (size_t)i*256 + 4);
            sA += (v2f){lv.x, lv.y};
            sB += (v2f){lv.z, lv.w};
            v2f p01 = {a0.x,a0.y}, p23 = {a0.z,a0.w};
            v2f p45 = {a1.x,a1.y}, p67 = {a1.z,a1.w};
            v2f w0 = {lv.x,lv.x}, w1 = {lv.y,lv.y};
            v2f w2 = {lv.z,lv.z}, w3 = {lv.w,lv.w};
            acc2[0][0]=pk_fma(w0,p01,acc2[0][0]); acc2[0][1]=pk_fma(w0,p23,acc2[0][1]);
            acc2[0][2]=pk_fma(w0,p45,acc2[0][2]); acc2[0][3]=pk_fma(w0,p67,acc2[0][3]);
            acc2[1][0]=pk_fma(w1,p01,acc2[1][0]); acc2[1][1]=pk_fma(w1,p23,acc2[1][1]);
            acc2[1][2]=pk_fma(w1,p45,acc2[1][2]); acc2[1][3]=pk_fma(w1,p67,acc2[1][3]);
            acc2[2][0]=pk_fma(w2,p01,acc2[2][0]); acc2[2][1]=pk_fma(w2,p23,acc2[2][1]);
            acc2[2][2]=pk_fma(w2,p45,acc2[2][2]); acc2[2][3]=pk_fma(w2,p67,acc2[2][3]);
            acc2[3][0]=pk_fma(w3,p01,acc2[3][0]); acc2[3][1]=pk_fma(w3,p23,acc2[3][1]);
            acc2[3][2]=pk_fma(w3,p45,acc2[3][2]); acc2[3][3]=pk_fma(w3,p67,acc2[3][3]);
        }
    }

    float s4[4] = {sA[0], sA[1], sB[0], sB[1]};

    // ---- ig-merge, single 64-slot buffer aliased on sLog, 3 rounds ----
    int r64 = t & 63;
    #pragma unroll
    for (int g = 3; g >= 1; --g){
        __syncthreads();
        if (ig == g){
            float* dst = sBuf + (size_t)r64*37;
            #pragma unroll
            for (int c=0;c<4;++c) dst[c] = s4[c];
            #pragma unroll
            for (int c=0;c<4;++c)
                #pragma unroll
                for (int e=0;e<4;++e){
                    dst[4 + c*8 + 2*e    ] = acc2[c][e][0];
                    dst[4 + c*8 + 2*e + 1] = acc2[c][e][1];
                }
        }
        __syncthreads();
        if (ig == 0){
            const float* src = sBuf + (size_t)t*37;
            #pragma unroll
            for (int c=0;c<4;++c) s4[c] += src[c];
            #pragma unroll
            for (int c=0;c<4;++c)
                #pragma unroll
                for (int e=0;e<4;++e){
                    acc2[c][e][0] += src[4 + c*8 + 2*e    ];
                    acc2[c][e][1] += src[4 + c*8 + 2*e + 1];
                }
        }
    }

    size_t bp = ((size_t)b*128 + jt)*SPLIT + sp;

    // ---- T reduction (sBuf reused; barrier separates from merge reads) ----
    __syncthreads();
    #pragma unroll
    for (int k=0;k<4;++k) sBuf[(il_w*8 + jl_w)*4 + k] = Tp[k];
    __syncthreads();
    if (t < 8){
        float T0=0,T1=0,T2=0,T3=0;
        for (int s2=0;s2<32;++s2){
            const float* p = sBuf + (s2*8+t)*4;
            T0+=p[0];T1+=p[1];T2+=p[2];T3+=p[3];
        }
        float* td = Tws + (bp*8 + t)*4;
        td[0]=T0; td[1]=T1; td[2]=T2; td[3]=T3;
    }

    // ---- partial outputs from ig==0 threads (t<64) ----
    if (ig == 0){
        if (dq == 0){                       // t = h*2+jh < 8
            #pragma unroll
            for (int c=0;c<4;++c)
                Sws[bp*32 + h*8 + jh*4 + c] = s4[c];
        }
        #pragma unroll
        for (int c=0;c<4;++c){
            float* dst = Pws + (((size_t)bp*8 + jh*4 + c)*32 + h*8 + dq)*8;
            float4* d4 = reinterpret_cast<float4*>(dst);
            d4[0] = make_float4(acc2[c][0][0],acc2[c][0][1],acc2[c][1][0],acc2[c][1][1]);
            d4[1] = make_float4(acc2[c][2][0],acc2[c][2][1],acc2[c][3][0],acc2[c][3][1]);
        }
    }
}

// ---- kernel 4: merge split partials, normalize, add gelu(g)@W_fcg ----
template<int SPLIT>
__global__ __launch_bounds__(256) void k_merge(
    const float* __restrict__ Pws, const float* __restrict__ Sws,
    const float* __restrict__ Tws,
    const float* __restrict__ Gd_ws, const float* __restrict__ cnt_ws,
    const float* __restrict__ W_ffn, const float* __restrict__ W_fcg,
    const float* __restrict__ b_fcg, float* __restrict__ out)
{
    int b  = blockIdx.x >> 7;
    int jt = blockIdx.x & 127;
    int j0 = jt*8;
    int t  = threadIdx.x;
    int jl = t >> 5, hd = t & 31, h = hd >> 3, dq = hd & 7;
    __shared__ float sG[8][8];

    size_t bp0 = ((size_t)b*128 + jt)*SPLIT;
    float s = 0.0f, acc[8] = {0,0,0,0,0,0,0,0};
    #pragma unroll
    for (int sp2=0; sp2<SPLIT; ++sp2){
        const float* p = Pws + ((bp0+sp2)*256 + t)*8;
        float4 p0 = *reinterpret_cast<const float4*>(p);
        float4 p1 = *reinterpret_cast<const float4*>(p+4);
        acc[0]+=p0.x; acc[1]+=p0.y; acc[2]+=p0.z; acc[3]+=p0.w;
        acc[4]+=p1.x; acc[5]+=p1.y; acc[6]+=p1.z; acc[7]+=p1.w;
        s += Sws[(bp0+sp2)*32 + h*8 + jl];
    }
    if (t < 8){
        float T[4] = {0,0,0,0};
        #pragma unroll
        for (int sp2=0; sp2<SPLIT; ++sp2){
            const float* tp = Tws + ((bp0+sp2)*8 + t)*4;
            #pragma unroll
            for (int k=0;k<4;++k) T[k]+=tp[k];
        }
        size_t cj = (size_t)b*1024 + j0 + t;
        float cf = cnt_ws[cj];
        float inv = __fdividef(1.0f, cf + 1.0f);
        #pragma unroll
        for (int kk=0;kk<8;++kk){
            float a = cf*Gd_ws[cj*8+kk];
            #pragma unroll
            for (int k=0;k<4;++k) a += T[k]*W_ffn[k*8+kk];
            sG[t][kk] = gelu_f(a*inv);
        }
    }
    __syncthreads();

    float rs = (s > 0.0f) ? (1.0f/s) : 0.0f;
    int col0 = h*64 + dq*8;
    float gg[8];
    #pragma unroll
    for (int kk=0;kk<8;++kk) gg[kk]=sG[jl][kk];
    float o[8];
    #pragma unroll
    for (int d2=0;d2<8;++d2){
        float a = b_fcg[col0+d2];
        #pragma unroll
        for (int kk=0;kk<8;++kk) a += gg[kk]*W_fcg[kk*256 + col0 + d2];
        o[d2] = acc[d2]*rs + a;
    }
    float* ob = out + ((size_t)b*1024 + j0 + jl)*256 + col0;
    float4* o4 = reinterpret_cast<float4*>(ob);
    o4[0] = make_float4(o[0],o[1],o[2],o[3]);
    o4[1] = make_float4(o[4],o[5],o[6],o[7]);
}

extern "C" void kernel_launch(void* const* d_in, const int* in_sizes, int n_in,
                              void* d_out, int out_size, void* d_ws, size_t ws_size,
                              hipStream_t stream)
{
    const float* prev  = (const float*)d_in[0];
    const float* curr  = (const float*)d_in[1];
    const int*   edges = (const int*)  d_in[2];
    const float* W_pre = (const float*)d_in[3];
    const float* b_pre = (const float*)d_in[4];
    const float* W_cur = (const float*)d_in[5];
    const float* b_cur = (const float*)d_in[6];
    const float* W_fuse= (const float*)d_in[7];
    const float* b_fuse= (const float*)d_in[8];
    const float* W_ffn = (const float*)d_in[9];
    const float* b_ffn = (const float*)d_in[10];
    const float* W_fcc = (const float*)d_in[11];
    const float* b_fcc = (const float*)d_in[12];
    const float* W_fcg = (const float*)d_in[13];
    const float* b_fcg = (const float*)d_in[14];
    float* out = (float*)d_out;

    float* u_ws   = (float*)d_ws;          // 16384 floats
    float* v_ws   = u_ws  + 16384;         // 16384
    float* Gd_ws  = v_ws  + 16384;         // 32768
    float* cnt_ws = Gd_ws + 32768;         // 4096
    float* Pws    = cnt_ws + 4096;
    const size_t base_f = 16384 + 16384 + 32768 + 4096;

    k_rows<<<dim3(2048), dim3(256), 0, stream>>>(prev, curr, W_pre, b_pre,
        W_cur, b_cur, W_fuse, b_fuse, u_ws, v_ws);
    k_cols<<<dim3(256), dim3(256), 0, stream>>>(edges, u_ws, v_ws,
        W_ffn, b_ffn, Gd_ws, cnt_ws);

    const size_t p4 = (size_t)4*128*4*256*8, s4v = (size_t)4*128*4*32,
                 t4 = (size_t)4*128*4*8*4;
    const size_t p2 = p4/2, s2v = s4v/2, t2 = t4/2;
    const size_t need4 = (base_f + p4 + s4v + t4) * 4;
    const size_t need2 = (base_f + p2 + s2v + t2) * 4;

    float* Sws = Pws + p4;
    float* Tws = Sws + s4v;

    if (ws_size >= need4){
        k_main<4><<<dim3(2048), dim3(256), 0, stream>>>(prev, edges, u_ws, v_ws,
            Gd_ws, W_ffn, W_fcc, b_fcc, Pws, Sws, Tws);
        k_merge<4><<<dim3(512), dim3(256), 0, stream>>>(Pws, Sws, Tws, Gd_ws,
            cnt_ws, W_ffn, W_fcg, b_fcg, out);
    } else if (ws_size >= need2){
        float* Sws2 = Pws + p2;
        float* Tws2 = Sws2 + s2v;
        k_main<2><<<dim3(1024), dim3(256), 0, stream>>>(prev, edges, u_ws, v_ws,
            Gd_ws, W_ffn, W_fcc, b_fcc, Pws, Sws2, Tws2);
        k_merge<2><<<dim3(512), dim3(256), 0, stream>>>(Pws, Sws2, Tws2, Gd_ws,
            cnt_ws, W_ffn, W_fcg, b_fcg, out);
    } else {
        const size_t p1 = p4/4, s1 = s4v/4;
        float* Sws1 = Pws + p1;
        float* Tws1 = Sws1 + s1;
        k_main<1><<<dim3(512), dim3(256), 0, stream>>>(prev, edges, u_ws, v_ws,
            Gd_ws, W_ffn, W_fcc, b_fcc, Pws, Sws1, Tws1);
        k_merge<1><<<dim3(512), dim3(256), 0, stream>>>(Pws, Sws1, Tws1, Gd_ws,
            cnt_ws, W_ffn, W_fcg, b_fcg, out);
    }
}

// Round 16
// 86.355 us; speedup vs baseline: 1.6885x; 1.4497x over previous
//
#include <hip/hip_runtime.h>

// ---------------------------------------------------------------------------
// B=4, N1=1024, N2=1024, D=256, H=4, Dh=64
//   u[b,i,4] = gelu(prev@W_pre+b_pre) @ W_fuse[0:6]
//   v[b,j,4] = gelu(curr@W_cur+b_cur) @ W_fuse[6:12] + b_fuse
//   Gd_j[8] = gelu(d_j)@W_ffn[4:8] + gelu(e_j)@W_ffn[8:12] + b_ffn
//   logits = gelu(gelu(c)@W_ffn[0:4] + Gd_j)@W_fcc + b_fcc
//   softmax over i WITHOUT max-subtraction (masked -> w=0); plain-sum partials
//   res = P @ prev (per-head);  g_j = (T_j@W_ffn[0:4]+cnt*Gd_j)/(cnt+1)
//   out = res + gelu(g)@W_fcg + b_fcg
// Round-15 lesson: wall = VALU-busy/0.55 across 5 rounds; occupancy tracks
//   VGPR not LDS. The lever is instruction count. PV = 2.1 TFLOP = 60% of
//   VALU stream -> move PV to bf16 MFMA (16x16x32): w written as bf16
//   A-fragments in LDS (XOR-swizzled), prev pre-transposed to bf16 prevT,
//   per-wave-per-head 4 N-tiles x 2 K-steps, acc in 16 f32 regs, no ig-merge.
//   w MUST be bf16 not f16 (exp(logit) range needs 8-bit exponent).
// Round-12: compaction dropped (LDS/VGPR cost); single-pass logit.
// Round-9: exp once at w-write. Round-6: denominators PER (column, HEAD).
// Round-5: VGPR cliffs at 64/128. Round-4: never cap min-waves.
// ---------------------------------------------------------------------------

using bf16x8 = __attribute__((ext_vector_type(8))) short;
using f32x4  = __attribute__((ext_vector_type(4))) float;

__device__ __forceinline__ float gelu_f(float x){
    float x2 = x*x;
    float tt = x * __builtin_fmaf(0.044715f, x2, 1.0f);   // x + 0.044715 x^3
    float e  = exp2f(2.3022082f * tt);                    // exp(1.59576912*tt)
    return x - __fdividef(x, e + 1.0f);
}

__device__ __forceinline__ unsigned short f2bf(float f){
    unsigned int u = __float_as_uint(f);
    u += 0x7FFFu + ((u >> 16) & 1u);                      // round-to-nearest
    return (unsigned short)(u >> 16);
}

// ---- kernel 0: prevT_bf16[b][d][i] = bf16(prev[b][i][d]) ----
// grid 256 = 4b x 16 i-tiles x 4 d-tiles; 64x64 LDS tile transpose.
__global__ __launch_bounds__(256) void k_prevT(
    const float* __restrict__ prev, unsigned short* __restrict__ prevT)
{
    int bid = blockIdx.x;
    int b  = bid >> 6;
    int it = (bid >> 2) & 15;
    int dt = bid & 3;
    int i0 = it*64, d0 = dt*64;
    int t = threadIdx.x;
    int col = t & 63, rw = t >> 6;
    __shared__ float tile[64][65];
    #pragma unroll
    for (int r = 0; r < 16; ++r){
        int row = rw + 4*r;
        tile[row][col] = prev[((size_t)b*1024 + i0 + row)*256 + d0 + col];
    }
    __syncthreads();
    #pragma unroll
    for (int r = 0; r < 16; ++r){
        int drow = rw + 4*r;
        prevT[((size_t)b*256 + d0 + drow)*1024 + i0 + col] = f2bf(tile[col][drow]);
    }
}

// ---- kernel 1: per-row u (prev side) and v (curr side), one wave per row ----
__global__ __launch_bounds__(256) void k_rows(
    const float* __restrict__ prev, const float* __restrict__ curr,
    const float* __restrict__ W_pre, const float* __restrict__ b_pre,
    const float* __restrict__ W_cur, const float* __restrict__ b_cur,
    const float* __restrict__ W_fuse, const float* __restrict__ b_fuse,
    float* __restrict__ u_ws, float* __restrict__ v_ws)
{
    int gid  = blockIdx.x * 256 + threadIdx.x;
    int wave = gid >> 6;
    int lane = threadIdx.x & 63;
    bool isPrev = wave < 4096;
    int row = isPrev ? wave : (wave - 4096);
    const float* xrow = (isPrev ? prev : curr) + (size_t)row * 256;
    const float* W  = isPrev ? W_pre : W_cur;
    const float* bv = isPrev ? b_pre : b_cur;

    float4 x4 = *reinterpret_cast<const float4*>(xrow + lane*4);
    const float* Wl = W + lane*24;
    float p[6];
    #pragma unroll
    for (int k=0;k<6;++k)
        p[k] = x4.x*Wl[k] + x4.y*Wl[6+k] + x4.z*Wl[12+k] + x4.w*Wl[18+k];
    #pragma unroll
    for (int off=32; off>=1; off>>=1){
        #pragma unroll
        for (int k=0;k<6;++k) p[k] += __shfl_xor(p[k], off, 64);
    }
    if (lane == 0){
        float g[6];
        #pragma unroll
        for(int k=0;k<6;++k) g[k] = gelu_f(p[k] + bv[k]);
        int rb = isPrev ? 0 : 6;
        float o[4];
        #pragma unroll
        for(int kk=0;kk<4;++kk){
            float a = isPrev ? 0.0f : b_fuse[kk];
            #pragma unroll
            for(int k=0;k<6;++k) a += g[k]*W_fuse[(rb+k)*4+kk];
            o[kk]=a;
        }
        float* dst = (isPrev ? u_ws : v_ws) + (size_t)row*4;
        *reinterpret_cast<float4*>(dst) = make_float4(o[0],o[1],o[2],o[3]);
    }
}

// ---- kernel 2: per-column reductions over edges + Gd precompute ----
__global__ __launch_bounds__(256) void k_cols(
    const int* __restrict__ edges,
    const float* __restrict__ u_ws, const float* __restrict__ v_ws,
    const float* __restrict__ W_ffn, const float* __restrict__ b_ffn,
    float* __restrict__ Gd_ws, float* __restrict__ cnt_ws)
{
    int b  = blockIdx.x >> 6;
    int j0 = (blockIdx.x & 63) * 16;
    int t  = threadIdx.x;
    int jq = t & 3, sl = t >> 2;
    const int*   eb = edges + (size_t)b*1048576 + j0 + jq*4;
    const float* ub = u_ws + (size_t)b*4096;

    int   cnt[4] = {0,0,0,0};
    float S[4][4] = {{0.f}};
    float M[4][4];
    #pragma unroll
    for (int q=0;q<4;++q)
        #pragma unroll
        for (int k=0;k<4;++k) M[q][k] = -3.4e38f;

    #pragma unroll 4
    for (int ii=0; ii<16; ++ii){
        int i = sl*16 + ii;
        int4   e4 = *reinterpret_cast<const int4*>(eb + (size_t)i*1024);
        float4 u4 = *reinterpret_cast<const float4*>(ub + i*4);
        float uu[4] = {u4.x,u4.y,u4.z,u4.w};
        int   ee[4] = {e4.x,e4.y,e4.z,e4.w};
        #pragma unroll
        for (int q=0;q<4;++q){
            bool mk = ee[q]!=0;
            cnt[q] += mk ? 1 : 0;
            #pragma unroll
            for (int k=0;k<4;++k){
                S[q][k] += mk ? uu[k] : 0.0f;
                M[q][k]  = mk ? fmaxf(M[q][k],uu[k]) : M[q][k];
            }
        }
    }
    __shared__ float rS[64][16][4];
    __shared__ float rM[64][16][4];
    __shared__ int   rC[64][16];
    #pragma unroll
    for (int q=0;q<4;++q){
        int c = jq*4+q;
        #pragma unroll
        for (int k=0;k<4;++k){ rS[sl][c][k]=S[q][k]; rM[sl][c][k]=M[q][k]; }
        rC[sl][c]=cnt[q];
    }
    __syncthreads();
    float aS[4], aM[4]; int aC=0; int c2=0, hf=0;
    if (t < 128){
        c2 = t & 15; hf = t >> 4;
        #pragma unroll
        for(int k=0;k<4;++k){ aS[k]=0.f; aM[k]=-3.4e38f; }
        for (int s2=hf*8; s2<hf*8+8; ++s2){
            aC += rC[s2][c2];
            #pragma unroll
            for(int k=0;k<4;++k){ aS[k]+=rS[s2][c2][k]; aM[k]=fmaxf(aM[k],rM[s2][c2][k]); }
        }
    }
    __syncthreads();
    if (t < 128){
        rC[hf][c2]=aC;
        #pragma unroll
        for(int k=0;k<4;++k){ rS[hf][c2][k]=aS[k]; rM[hf][c2][k]=aM[k]; }
    }
    __syncthreads();
    if (t < 16){
        int cc=0; float Sa[4]={0,0,0,0};
        float Ma[4]={-3.4e38f,-3.4e38f,-3.4e38f,-3.4e38f};
        for (int s2=0;s2<8;++s2){
            cc += rC[s2][t];
            #pragma unroll
            for(int k=0;k<4;++k){ Sa[k]+=rS[s2][t][k]; Ma[k]=fmaxf(Ma[k],rM[s2][t][k]); }
        }
        size_t cj = (size_t)b*1024 + j0 + t;
        float4 v4 = *reinterpret_cast<const float4*>(v_ws + cj*4);
        float vv[4]={v4.x,v4.y,v4.z,v4.w};
        float cf = (float)cc, e1 = cf + 1.0f;
        float gd[4], ge[4];
        #pragma unroll
        for(int k=0;k<4;++k){
            float dk = (Sa[k] + cf*vv[k]) / e1;
            float ek;
            if (cc == 0) ek = 0.0f;
            else { float m1 = Ma[k]+vv[k]; ek = (cc < 1024) ? fmaxf(m1, 0.0f) : m1; }
            gd[k]=gelu_f(dk); ge[k]=gelu_f(ek);
        }
        #pragma unroll
        for(int kk=0;kk<8;++kk){
            float a = b_ffn[kk];
            #pragma unroll
            for(int k=0;k<4;++k)
                a += gd[k]*W_ffn[(4+k)*8+kk] + ge[k]*W_ffn[(8+k)*8+kk];
            Gd_ws[cj*8+kk]=a;
        }
        cnt_ws[cj]=cf;
    }
}

// ---- kernel 3: logits (fp32) -> bf16 A-fragments in LDS; MFMA PV ----
// Block = (b, jtile of 8 cols, sp i-part). 256 threads, grid 4*128*SPLIT.
// Logit role: (il_w=t>>3 in 0..31, jl_w=t&7) -> writes w bf16 to wA.
// PV role: wave wv = head h; 4 N-tiles(16 dims) x 2 K-steps(32) of
//   v_mfma_f32_16x16x32_bf16; A from wA (ds_read_b128, XOR-swizzled),
//   B from prevT_bf16 (global dwordx4). acc f32x4[4] across all chunks.
// wA rows 8..15 zeroed once (M padded 8->16); D rows 8..15 ignored.
template<int SPLIT>
__global__ __launch_bounds__(256) void k_main(
    const unsigned short* __restrict__ prevT, const int* __restrict__ edges,
    const float* __restrict__ u_ws, const float* __restrict__ v_ws,
    const float* __restrict__ Gd_ws,
    const float* __restrict__ W_ffn, const float* __restrict__ W_fcc,
    const float* __restrict__ b_fcc,
    float* __restrict__ Pws, float* __restrict__ Sws, float* __restrict__ Tws)
{
    const int RPB = 1024/SPLIT;
    int bid = blockIdx.x;
    int sp  = bid & (SPLIT-1);
    int jt  = (bid / SPLIT) & 127;
    int b   = bid / (SPLIT*128);
    int j0  = jt*8;
    int t   = threadIdx.x;
    int lane = t & 63;
    int wv   = t >> 6;                       // PV: wave = head
    int jl_w = t & 7, il_w = t >> 3;

    __shared__ unsigned short wA[4096];      // [h][row16][k64] bf16, swizzled
    __shared__ __align__(16) float sU[64][4];
    __shared__ float sV[8][4];
    __shared__ float sGd[8][8];
    __shared__ float sTS[2048];              // tail: [il_w32][jl_w8][T4|S4]

    if (t < 32) (&sV[0][0])[t]  = v_ws[((size_t)b*1024 + j0)*4 + t];
    if (t < 64) (&sGd[0][0])[t] = Gd_ws[((size_t)b*1024 + j0)*8 + t];
    {   // zero all of wA (rows 8..15 stay zero forever)
        unsigned int* wz = (unsigned int*)wA;
        #pragma unroll
        for (int z=0; z<8; ++z) wz[t + z*256] = 0u;
    }

    const float LOG2E = 1.4426950408889634f;
    float W4r[4][8], Wfc[8][4], bfc[4];
    #pragma unroll
    for(int k=0;k<4;++k)
        #pragma unroll
        for(int kk=0;kk<8;++kk) W4r[k][kk]=W_ffn[k*8+kk];
    #pragma unroll
    for(int kk=0;kk<8;++kk)
        #pragma unroll
        for(int hh=0;hh<4;++hh) Wfc[kk][hh]=W_fcc[kk*4+hh]*LOG2E;
    #pragma unroll
    for(int hh=0;hh<4;++hh) bfc[hh]=b_fcc[hh]*LOG2E;

    f32x4 accm[4];
    #pragma unroll
    for (int tile=0;tile<4;++tile) accm[tile] = (f32x4){0.f,0.f,0.f,0.f};
    float Tp[4] = {0,0,0,0};
    float Sp[4] = {0,0,0,0};

    const int* ebase = edges + (size_t)b*1048576 + j0;
    const int NCH = RPB/64;
    const int base_i0 = sp*RPB;

    __syncthreads();                          // sV/sGd/wA-zero visible
    float4 v4p = *reinterpret_cast<const float4*>(&sV[jl_w][0]);
    float4 gd0 = *reinterpret_cast<const float4*>(&sGd[jl_w][0]);
    float4 gd1 = *reinterpret_cast<const float4*>(&sGd[jl_w][4]);

    // PV addressing (constant over chunks)
    int arow = lane & 15, kgrp = lane >> 4;
    int aoff0 = (((wv*16 + arow)*64 + kgrp*8)*2) ^ ((arow & 7) << 4);
    int aoff1 = aoff0 ^ 64;                   // +32 ushorts = +64 bytes (bit6)
    const unsigned short* pTbase = prevT
        + ((size_t)b*256 + wv*64 + arow)*1024 + base_i0 + kgrp*8;

    // ---- prologue prefetch for chunk 0 ----
    float su_r = u_ws[((size_t)b*1024 + base_i0)*4 + t];
    int   egr0 = ebase[(size_t)(base_i0+il_w   )*1024 + jl_w];
    int   egr1 = ebase[(size_t)(base_i0+il_w+32)*1024 + jl_w];

    for (int cc=0; cc<NCH; ++cc){
        (&sU[0][0])[t] = su_r;                // publish prefetched sU
        __syncthreads();                      // B1: sU visible; prior PV done

        // ---- logit phase: 2 rows per thread; w -> bf16 into wA ----
        int eg2[2] = {egr0, egr1};
        #pragma unroll
        for (int r=0;r<2;++r){
            int il = il_w + 32*r;
            int eg = eg2[r];
            float4 u4 = *reinterpret_cast<const float4*>(&sU[il][0]);
            float g0 = gelu_f(u4.x + v4p.x);
            float g1 = gelu_f(u4.y + v4p.y);
            float g2 = gelu_f(u4.z + v4p.z);
            float g3 = gelu_f(u4.w + v4p.w);
            Tp[0] += eg ? g0 : 0.0f;
            Tp[1] += eg ? g1 : 0.0f;
            Tp[2] += eg ? g2 : 0.0f;
            Tp[3] += eg ? g3 : 0.0f;
            float gdv[8] = {gd0.x,gd0.y,gd0.z,gd0.w,gd1.x,gd1.y,gd1.z,gd1.w};
            float fu[8];
            #pragma unroll
            for(int kk=0;kk<8;++kk){
                float a = gdv[kk];
                a = __builtin_fmaf(g0, W4r[0][kk], a);
                a = __builtin_fmaf(g1, W4r[1][kk], a);
                a = __builtin_fmaf(g2, W4r[2][kk], a);
                a = __builtin_fmaf(g3, W4r[3][kk], a);
                fu[kk] = gelu_f(a);
            }
            #pragma unroll
            for(int hh=0;hh<4;++hh){
                float a = bfc[hh];
                #pragma unroll
                for(int kk=0;kk<8;++kk) a = __builtin_fmaf(fu[kk], Wfc[kk][hh], a);
                float wf = eg ? exp2f(a) : 0.0f;
                Sp[hh] += wf;
                int boff = ((((hh*16 + jl_w)*64) + il)*2) ^ ((jl_w & 7) << 4);
                *reinterpret_cast<unsigned short*>(
                    reinterpret_cast<char*>(wA) + boff) = f2bf(wf);
            }
        }

        // ---- prefetch next chunk ----
        {
            int i0n = base_i0 + ((cc+1 < NCH) ? (cc+1)*64 : 0);
            su_r = u_ws[((size_t)b*1024 + i0n)*4 + t];
            egr0 = ebase[(size_t)(i0n+il_w   )*1024 + jl_w];
            egr1 = ebase[(size_t)(i0n+il_w+32)*1024 + jl_w];
        }
        __syncthreads();                      // B2: wA ready

        // ---- PV: 2 A-frags shared across 4 N-tiles; 8 MFMA ----
        bf16x8 afr0 = *reinterpret_cast<const bf16x8*>(
            reinterpret_cast<const char*>(wA) + aoff0);
        bf16x8 afr1 = *reinterpret_cast<const bf16x8*>(
            reinterpret_cast<const char*>(wA) + aoff1);
        const unsigned short* pT = pTbase + (size_t)cc*64;
        #pragma unroll
        for (int tile=0; tile<4; ++tile){
            const unsigned short* pB = pT + (size_t)tile*16*1024;
            bf16x8 bfr0 = *reinterpret_cast<const bf16x8*>(pB);
            bf16x8 bfr1 = *reinterpret_cast<const bf16x8*>(pB + 32);
            accm[tile] = __builtin_amdgcn_mfma_f32_16x16x32_bf16(
                afr0, bfr0, accm[tile], 0, 0, 0);
            accm[tile] = __builtin_amdgcn_mfma_f32_16x16x32_bf16(
                afr1, bfr1, accm[tile], 0, 0, 0);
        }
    }

    size_t bp = ((size_t)b*128 + jt)*SPLIT + sp;

    // ---- tail: T and S reductions ----
    {
        float* ts = sTS + (size_t)(il_w*8 + jl_w)*8;
        #pragma unroll
        for (int k=0;k<4;++k){ ts[k] = Tp[k]; ts[4+k] = Sp[k]; }
    }
    __syncthreads();
    if (t < 8){
        float T[4]={0,0,0,0}, S[4]={0,0,0,0};
        for (int s2=0;s2<32;++s2){
            const float* p = sTS + (size_t)(s2*8 + t)*8;
            #pragma unroll
            for (int k=0;k<4;++k){ T[k]+=p[k]; S[k]+=p[4+k]; }
        }
        float* td = Tws + (bp*8 + t)*4;
        td[0]=T[0]; td[1]=T[1]; td[2]=T[2]; td[3]=T[3];
        #pragma unroll
        for (int hh=0;hh<4;++hh) Sws[bp*32 + hh*8 + t] = S[hh];
    }

    // ---- epilogue: D rows 0..7 = cols j; write Pws[bp][j][256] ----
    if (kgrp < 2){
        #pragma unroll
        for (int tile=0; tile<4; ++tile){
            #pragma unroll
            for (int r2=0; r2<4; ++r2){
                int j   = kgrp*4 + r2;
                int dim = wv*64 + tile*16 + arow;
                Pws[((size_t)bp*8 + j)*256 + dim] = accm[tile][r2];
            }
        }
    }
}

// ---- kernel 4: merge split partials, normalize, add gelu(g)@W_fcg ----
template<int SPLIT>
__global__ __launch_bounds__(256) void k_merge(
    const float* __restrict__ Pws, const float* __restrict__ Sws,
    const float* __restrict__ Tws,
    const float* __restrict__ Gd_ws, const float* __restrict__ cnt_ws,
    const float* __restrict__ W_ffn, const float* __restrict__ W_fcg,
    const float* __restrict__ b_fcg, float* __restrict__ out)
{
    int b  = blockIdx.x >> 7;
    int jt = blockIdx.x & 127;
    int j0 = jt*8;
    int t  = threadIdx.x;
    int jl = t >> 5, hd = t & 31, h = hd >> 3, dq = hd & 7;
    __shared__ float sG[8][8];

    size_t bp0 = ((size_t)b*128 + jt)*SPLIT;
    float s = 0.0f, acc[8] = {0,0,0,0,0,0,0,0};
    #pragma unroll
    for (int sp2=0; sp2<SPLIT; ++sp2){
        const float* p = Pws + ((bp0+sp2)*8 + jl)*256 + hd*8;
        float4 p0 = *reinterpret_cast<const float4*>(p);
        float4 p1 = *reinterpret_cast<const float4*>(p+4);
        acc[0]+=p0.x; acc[1]+=p0.y; acc[2]+=p0.z; acc[3]+=p0.w;
        acc[4]+=p1.x; acc[5]+=p1.y; acc[6]+=p1.z; acc[7]+=p1.w;
        s += Sws[(bp0+sp2)*32 + h*8 + jl];
    }
    if (t < 8){
        float T[4] = {0,0,0,0};
        #pragma unroll
        for (int sp2=0; sp2<SPLIT; ++sp2){
            const float* tp = Tws + ((bp0+sp2)*8 + t)*4;
            #pragma unroll
            for (int k=0;k<4;++k) T[k]+=tp[k];
        }
        size_t cj = (size_t)b*1024 + j0 + t;
        float cf = cnt_ws[cj];
        float inv = __fdividef(1.0f, cf + 1.0f);
        #pragma unroll
        for (int kk=0;kk<8;++kk){
            float a = cf*Gd_ws[cj*8+kk];
            #pragma unroll
            for (int k=0;k<4;++k) a += T[k]*W_ffn[k*8+kk];
            sG[t][kk] = gelu_f(a*inv);
        }
    }
    __syncthreads();

    float rs = (s > 0.0f) ? (1.0f/s) : 0.0f;
    int col0 = h*64 + dq*8;
    float gg[8];
    #pragma unroll
    for (int kk=0;kk<8;++kk) gg[kk]=sG[jl][kk];
    float o[8];
    #pragma unroll
    for (int d2=0;d2<8;++d2){
        float a = b_fcg[col0+d2];
        #pragma unroll
        for (int kk=0;kk<8;++kk) a += gg[kk]*W_fcg[kk*256 + col0 + d2];
        o[d2] = acc[d2]*rs + a;
    }
    float* ob = out + ((size_t)b*1024 + j0 + jl)*256 + col0;
    float4* o4 = reinterpret_cast<float4*>(ob);
    o4[0] = make_float4(o[0],o[1],o[2],o[3]);
    o4[1] = make_float4(o[4],o[5],o[6],o[7]);
}

extern "C" void kernel_launch(void* const* d_in, const int* in_sizes, int n_in,
                              void* d_out, int out_size, void* d_ws, size_t ws_size,
                              hipStream_t stream)
{
    const float* prev  = (const float*)d_in[0];
    const float* curr  = (const float*)d_in[1];
    const int*   edges = (const int*)  d_in[2];
    const float* W_pre = (const float*)d_in[3];
    const float* b_pre = (const float*)d_in[4];
    const float* W_cur = (const float*)d_in[5];
    const float* b_cur = (const float*)d_in[6];
    const float* W_fuse= (const float*)d_in[7];
    const float* b_fuse= (const float*)d_in[8];
    const float* W_ffn = (const float*)d_in[9];
    const float* b_ffn = (const float*)d_in[10];
    const float* W_fcc = (const float*)d_in[11];
    const float* b_fcc = (const float*)d_in[12];
    const float* W_fcg = (const float*)d_in[13];
    const float* b_fcg = (const float*)d_in[14];
    float* out = (float*)d_out;

    float* u_ws   = (float*)d_ws;          // 16384 floats
    float* v_ws   = u_ws  + 16384;         // 16384
    float* Gd_ws  = v_ws  + 16384;         // 32768
    float* cnt_ws = Gd_ws + 32768;         // 4096
    float* Pws    = cnt_ws + 4096;
    const size_t base_f = 16384 + 16384 + 32768 + 4096;

    const size_t p4  = (size_t)4*128*4*8*256;     // 4,194,304 floats
    const size_t s4v = (size_t)4*128*4*32;        // 65,536
    const size_t t4  = (size_t)4*128*4*8*4;       // 65,536... (8 cols x4)
    const size_t pT_f = (size_t)4*256*1024/2;     // 1M ushorts = 524,288 floats
    const size_t need4 = (base_f + p4 + s4v + t4 + pT_f) * 4;
    const size_t p2 = p4/2, s2v = s4v/2, t2 = t4/2;
    const size_t need2 = (base_f + p2 + s2v + t2 + pT_f) * 4;
    const size_t p1 = p4/4, s1 = s4v/4, t1 = t4/4;
    const size_t need1 = (base_f + p1 + s1 + t1 + pT_f) * 4;

    k_rows<<<dim3(2048), dim3(256), 0, stream>>>(prev, curr, W_pre, b_pre,
        W_cur, b_cur, W_fuse, b_fuse, u_ws, v_ws);
    k_cols<<<dim3(256), dim3(256), 0, stream>>>(edges, u_ws, v_ws,
        W_ffn, b_ffn, Gd_ws, cnt_ws);

    if (ws_size >= need4){
        float* Sws = Pws + p4;
        float* Tws = Sws + s4v;
        unsigned short* prevT = (unsigned short*)(Tws + t4);
        k_prevT<<<dim3(256), dim3(256), 0, stream>>>(prev, prevT);
        k_main<4><<<dim3(2048), dim3(256), 0, stream>>>(prevT, edges, u_ws,
            v_ws, Gd_ws, W_ffn, W_fcc, b_fcc, Pws, Sws, Tws);
        k_merge<4><<<dim3(512), dim3(256), 0, stream>>>(Pws, Sws, Tws, Gd_ws,
            cnt_ws, W_ffn, W_fcg, b_fcg, out);
    } else if (ws_size >= need2){
        float* Sws = Pws + p2;
        float* Tws = Sws + s2v;
        unsigned short* prevT = (unsigned short*)(Tws + t2);
        k_prevT<<<dim3(256), dim3(256), 0, stream>>>(prev, prevT);
        k_main<2><<<dim3(1024), dim3(256), 0, stream>>>(prevT, edges, u_ws,
            v_ws, Gd_ws, W_ffn, W_fcc, b_fcc, Pws, Sws, Tws);
        k_merge<2><<<dim3(512), dim3(256), 0, stream>>>(Pws, Sws, Tws, Gd_ws,
            cnt_ws, W_ffn, W_fcg, b_fcg, out);
    } else {
        float* Sws = Pws + p1;
        float* Tws = Sws + s1;
        unsigned short* prevT = (unsigned short*)(Tws + t1);
        k_prevT<<<dim3(256), dim3(256), 0, stream>>>(prev, prevT);
        k_main<1><<<dim3(512), dim3(256), 0, stream>>>(prevT, edges, u_ws,
            v_ws, Gd_ws, W_ffn, W_fcc, b_fcc, Pws, Sws, Tws);
        k_merge<1><<<dim3(512), dim3(256), 0, stream>>>(Pws, Sws, Tws, Gd_ws,
            cnt_ws, W_ffn, W_fcg, b_fcg, out);
    }
}